// Round 4
// baseline (460.949 us; speedup 1.0000x reference)
//
#include <hip/hip_runtime.h>

#define EPSQ 1e-8f

// x: (32, 32, 192, 192) f32; weight: (32, 32, 3, 3) f32; bias: (32,) f32; bits: (32,) i32

// ---------------- Kernel A: per-(batch, chunk) min/max partials ----------------
__global__ __launch_bounds__(256) void kA_partial_minmax(
    const float* __restrict__ x, float* __restrict__ partials)
{
    const int batch = blockIdx.x / 36;
    const int blk   = blockIdx.x % 36;
    const float* xb = x + (size_t)batch * 1179648 + (size_t)blk * 32768;
    float mn = INFINITY, mx = -INFINITY;
#pragma unroll
    for (int i = 0; i < 32; ++i) {
        const float4 v = reinterpret_cast<const float4*>(xb)[i * 256 + threadIdx.x];
        mn = fminf(mn, fminf(fminf(v.x, v.y), fminf(v.z, v.w)));
        mx = fmaxf(mx, fmaxf(fmaxf(v.x, v.y), fmaxf(v.z, v.w)));
    }
    __shared__ float smn[256], smx[256];
    smn[threadIdx.x] = mn; smx[threadIdx.x] = mx;
    __syncthreads();
    for (int s = 128; s > 0; s >>= 1) {
        if (threadIdx.x < s) {
            smn[threadIdx.x] = fminf(smn[threadIdx.x], smn[threadIdx.x + s]);
            smx[threadIdx.x] = fmaxf(smx[threadIdx.x], smx[threadIdx.x + s]);
        }
        __syncthreads();
    }
    if (threadIdx.x == 0) {
        partials[blockIdx.x * 2 + 0] = smn[0];
        partials[blockIdx.x * 2 + 1] = smx[0];
    }
}

// ---------------- Kernel B: group stats + quantized transposed weights ----------------
// gstats[g*2+0]=mn_g, gstats[g*2+1]=scale_g  (g: 0->b=2, 1->b=4, 2->b=8)
// wq_t[g][(ci*9 + k)*32 + co], co contiguous
__global__ __launch_bounds__(256) void kB_stats_and_wq(
    const float* __restrict__ w, const int* __restrict__ bits,
    const float* __restrict__ partials, float* __restrict__ gstats,
    float* __restrict__ wq_t)
{
    __shared__ float bmn[32], bmx[32];
    __shared__ float red[256];
    __shared__ float s_wmn, s_wmx;
    const int tid = threadIdx.x;

    if (tid < 32) {
        float mn = INFINITY, mx = -INFINITY;
        for (int i = 0; i < 36; ++i) {
            mn = fminf(mn, partials[(tid * 36 + i) * 2 + 0]);
            mx = fmaxf(mx, partials[(tid * 36 + i) * 2 + 1]);
        }
        bmn[tid] = mn; bmx[tid] = mx;
    }

    float wmn = INFINITY, wmx = -INFINITY;
    for (int i = tid; i < 9216; i += 256) {
        const float v = w[i];
        wmn = fminf(wmn, v); wmx = fmaxf(wmx, v);
    }
    red[tid] = wmn; __syncthreads();
    for (int s = 128; s > 0; s >>= 1) { if (tid < s) red[tid] = fminf(red[tid], red[tid + s]); __syncthreads(); }
    if (tid == 0) s_wmn = red[0];
    __syncthreads();
    red[tid] = wmx; __syncthreads();
    for (int s = 128; s > 0; s >>= 1) { if (tid < s) red[tid] = fmaxf(red[tid], red[tid + s]); __syncthreads(); }
    if (tid == 0) s_wmx = red[0];
    __syncthreads();

    if (tid < 3) {
        const int bval = 2 << tid;
        const float denom = (float)((1 << bval) - 1);
        float mn = INFINITY, mx = -INFINITY; bool has = false;
        for (int nb = 0; nb < 32; ++nb) {
            if (bits[nb] == bval) { has = true; mn = fminf(mn, bmn[nb]); mx = fmaxf(mx, bmx[nb]); }
        }
        if (!has) { mn = 0.f; mx = 0.f; }
        const float scale = fmaxf((mx - mn) / denom, EPSQ);
        gstats[tid * 2 + 0] = mn;
        gstats[tid * 2 + 1] = scale;
    }

    const float wmnv = s_wmn, wmxv = s_wmx;
    for (int g = 0; g < 3; ++g) {
        const int bval = 2 << g;
        const float denom = (float)((1 << bval) - 1);
        const float wsc = fmaxf((wmxv - wmnv) / denom, EPSQ);
        for (int i = tid; i < 9216; i += 256) {
            const int co = i / 288;
            const int rem = i % 288;
            const float v = w[i];
            const float q = rintf((v - wmnv) / wsc) * wsc + wmnv;
            wq_t[g * 9216 + rem * 32 + co] = q;
        }
    }
}

// ---------------- Kernel C: quantize-on-load conv3x3 ----------------
// grid = (6, 6, 32); block = 256 (4 waves).
// Block tile: 32 rows x 32 cols x all 32 co. Thread: 8 co x (4 rows x 4 cols) = 128 out.
// ci staged in quarters of 8 -> LDS = 38.25 (xq, stride-36 rows) + 9 (w) = 47.25 KB.
// Occupancy: VGPR-bound 2 blocks/CU (launch_bounds(256,2) -> ~256 VGPR budget).
// x LDS stride 36: 8-lane b128 phase groups tile all 32 banks (conflict-free).
__global__ __launch_bounds__(256, 2) void kC_conv(
    const float* __restrict__ x, const float* __restrict__ bias,
    const int* __restrict__ bits, const float* __restrict__ gstats,
    const float* __restrict__ wq_t, float* __restrict__ out)
{
    __shared__ float xq[8][34][36];   // [ci][row+halo][col+halo, pad 34->36]
    __shared__ float wlq[2304];       // [ci][tap][co] for current quarter

    const int n  = blockIdx.z;
    const int oy = blockIdx.y * 32;
    const int ox = blockIdx.x * 32;
    const int tid = threadIdx.x;

    const int bval = bits[n];
    const int g = (bval == 2) ? 0 : (bval == 4 ? 1 : 2);
    const float mn    = gstats[g * 2 + 0];
    const float scale = gstats[g * 2 + 1];

    const int co_g = tid >> 6;        // 0..3 -> co base = co_g*8
    const int lane = tid & 63;
    const int rg   = lane >> 3;       // 0..7 -> output rows 4rg..4rg+3
    const int cq   = lane & 7;        // 0..7 -> output cols 4cq..4cq+3

    float acc[8][16];                 // [co][r4*4+j]
#pragma unroll
    for (int c = 0; c < 8; ++c)
#pragma unroll
        for (int j = 0; j < 16; ++j) acc[c][j] = 0.f;

    const float* xn = x + (size_t)n * 32 * 192 * 192;

    for (int q = 0; q < 4; ++q) {
        __syncthreads();              // previous quarter's consumers done
        const int ci0 = q * 8;

        // stage weights for this quarter (linear copy)
        const float* wsrc = wq_t + g * 9216 + ci0 * 288;
        for (int i = tid; i < 2304; i += 256) wlq[i] = wsrc[i];

        // stage + quantize x quarter: 8 ci x 34 rows x 34 cols
        for (int idx = tid; idx < 9248; idx += 256) {
            const int ci  = idx / 1156;            // 34*34
            const int rem = idx - ci * 1156;
            const int r   = rem / 34;
            const int c   = rem - r * 34;
            const int gy = oy + r - 1, gx = ox + c - 1;
            float v = 0.f;                          // conv pads x_q with exact 0
            if ((unsigned)gy < 192u && (unsigned)gx < 192u) {
                v = xn[((size_t)(ci0 + ci) * 192 + gy) * 192 + gx];
                v = rintf((v - mn) / scale) * scale + mn;  // IEEE div: matches ref
            }
            xq[ci][r][c] = v;
        }
        __syncthreads();

#pragma unroll 1
        for (int ci = 0; ci < 8; ++ci) {
            float xr[6][8];
#pragma unroll
            for (int dr = 0; dr < 6; ++dr) {
                *(float4*)&xr[dr][0] = *(const float4*)&xq[ci][4 * rg + dr][4 * cq];
                *(float4*)&xr[dr][4] = *(const float4*)&xq[ci][4 * rg + dr][4 * cq + 4];
            }
#pragma unroll
            for (int kh = 0; kh < 3; ++kh) {
#pragma unroll
                for (int kw = 0; kw < 3; ++kw) {
                    const float* wp = &wlq[(ci * 9 + kh * 3 + kw) * 32 + co_g * 8];
                    const float4 w0 = *(const float4*)(wp + 0);
                    const float4 w1 = *(const float4*)(wp + 4);
                    const float wv[8] = {w0.x, w0.y, w0.z, w0.w, w1.x, w1.y, w1.z, w1.w};
#pragma unroll
                    for (int c = 0; c < 8; ++c) {
#pragma unroll
                        for (int r4 = 0; r4 < 4; ++r4) {
#pragma unroll
                            for (int j = 0; j < 4; ++j)
                                acc[c][r4 * 4 + j] += xr[r4 + kh][j + kw] * wv[c];
                        }
                    }
                }
            }
        }
    }

    // epilogue: bias + store (4 float4 per co)
#pragma unroll
    for (int c = 0; c < 8; ++c) {
        const int co = co_g * 8 + c;
        const float bv = bias[co];
#pragma unroll
        for (int r4 = 0; r4 < 4; ++r4) {
            float4 v;
            v.x = acc[c][r4 * 4 + 0] + bv;
            v.y = acc[c][r4 * 4 + 1] + bv;
            v.z = acc[c][r4 * 4 + 2] + bv;
            v.w = acc[c][r4 * 4 + 3] + bv;
            *(float4*)&out[(((size_t)n * 32 + co) * 192 + (oy + 4 * rg + r4)) * 192 + ox + 4 * cq] = v;
        }
    }
}

extern "C" void kernel_launch(void* const* d_in, const int* in_sizes, int n_in,
                              void* d_out, int out_size, void* d_ws, size_t ws_size,
                              hipStream_t stream) {
    const float* x      = (const float*)d_in[0];
    const float* weight = (const float*)d_in[1];
    const float* bias   = (const float*)d_in[2];
    const int*   bits   = (const int*)d_in[3];
    float* out = (float*)d_out;

    float* ws       = (float*)d_ws;
    float* partials = ws;            // 32*36*2 = 2304 floats
    float* gstats   = ws + 2304;     // 8 floats
    float* wq_t     = ws + 2312;     // 3*9216 floats

    kA_partial_minmax<<<32 * 36, 256, 0, stream>>>(x, partials);
    kB_stats_and_wq<<<1, 256, 0, stream>>>(weight, bits, partials, gstats, wq_t);

    dim3 grid(6, 6, 32);
    kC_conv<<<grid, 256, 0, stream>>>(x, bias, bits, gstats, wq_t, out);
}

// Round 5
// 335.247 us; speedup vs baseline: 1.3750x; 1.3750x over previous
//
#include <hip/hip_runtime.h>

#define EPSQ 1e-8f

typedef int v4i  __attribute__((ext_vector_type(4)));
typedef int v16i __attribute__((ext_vector_type(16)));

// x: (32, 32, 192, 192) f32; weight: (32, 32, 3, 3) f32; bias: (32,) f32; bits: (32,) i32
//
// Integer-exact decomposition (per batch n with group g, σ=2^(b-1)):
//   x_q = mn + s·k,  w_q = wm + t·j,  kc = k−σ, jc = j−σ  (i8, centered)
//   y[p,co] = s·t·KJ[p,co] + s·(wm+σt)·K1[p] + Tbl[class(p)][co]
//   KJ = Σ_{taps,ci} kc·jc  (i8 MFMA, exact i32; pad kc=0)
//   K1 = Σ_{taps,ci} kc     (box sum of per-pixel ci-sums; pad 0)
//   Tbl absorbs: t·A·ΣΣjc + 288·A·B + bias − A·(invalid-tap correction), A=mn+σs, B=wm+σt
// k and j use the same IEEE f32 div + rintf as the reference → identical quant decisions.

__device__ __forceinline__ int bytesum4(int v) {
#if __has_builtin(__builtin_amdgcn_sdot4)
    return __builtin_amdgcn_sdot4(v, 0x01010101, 0, false);
#else
    return (int)(char)(v) + (int)(char)(v >> 8) + (int)(char)(v >> 16) + (int)(char)(v >> 24);
#endif
}

// ---------------- Kernel A: per-(batch, chunk) min/max partials ----------------
__global__ __launch_bounds__(256) void kA_partial_minmax(
    const float* __restrict__ x, float* __restrict__ partials)
{
    const int batch = blockIdx.x / 36;
    const int blk   = blockIdx.x % 36;
    const float* xb = x + (size_t)batch * 1179648 + (size_t)blk * 32768;
    float mn = INFINITY, mx = -INFINITY;
#pragma unroll
    for (int i = 0; i < 32; ++i) {
        const float4 v = reinterpret_cast<const float4*>(xb)[i * 256 + threadIdx.x];
        mn = fminf(mn, fminf(fminf(v.x, v.y), fminf(v.z, v.w)));
        mx = fmaxf(mx, fmaxf(fmaxf(v.x, v.y), fmaxf(v.z, v.w)));
    }
    __shared__ float smn[256], smx[256];
    smn[threadIdx.x] = mn; smx[threadIdx.x] = mx;
    __syncthreads();
    for (int s = 128; s > 0; s >>= 1) {
        if (threadIdx.x < s) {
            smn[threadIdx.x] = fminf(smn[threadIdx.x], smn[threadIdx.x + s]);
            smx[threadIdx.x] = fmaxf(smx[threadIdx.x], smx[threadIdx.x + s]);
        }
        __syncthreads();
    }
    if (threadIdx.x == 0) {
        partials[blockIdx.x * 2 + 0] = smn[0];
        partials[blockIdx.x * 2 + 1] = smx[0];
    }
}

// ---------------- Kernel B: stats, tables, packed i8 weights ----------------
// gstats[g*2+{0,1}] = mn_g, s_g
// coefs[g*2+{0,1}]  = C1 = s·t, C2 = s·(wm+σt)
// tbl[g*288 + cls*32 + co]
// wq8[((g*9+tap)*64+lane)*16 + i] : A-frag bytes, lane: co=lane&31, ci=(lane>>5)*16+i
__global__ __launch_bounds__(256) void kB_stats_and_wq(
    const float* __restrict__ w, const float* __restrict__ bias,
    const int* __restrict__ bits, const float* __restrict__ partials,
    float* __restrict__ gstats, float* __restrict__ coefs,
    float* __restrict__ tbl, unsigned int* __restrict__ wq8)
{
    __shared__ float bmn[32], bmx[32];
    __shared__ float red[256];
    __shared__ float s_wmn, s_wmx;
    __shared__ float s_gmn[3], s_gs[3];
    __shared__ int   s_colJ[864];          // [g][tap][co] = Σ_ci jc
    const int tid = threadIdx.x;

    if (tid < 32) {
        float mn = INFINITY, mx = -INFINITY;
        for (int i = 0; i < 36; ++i) {
            mn = fminf(mn, partials[(tid * 36 + i) * 2 + 0]);
            mx = fmaxf(mx, partials[(tid * 36 + i) * 2 + 1]);
        }
        bmn[tid] = mn; bmx[tid] = mx;
    }

    float wmn = INFINITY, wmx = -INFINITY;
    for (int i = tid; i < 9216; i += 256) {
        const float v = w[i];
        wmn = fminf(wmn, v); wmx = fmaxf(wmx, v);
    }
    red[tid] = wmn; __syncthreads();
    for (int s = 128; s > 0; s >>= 1) { if (tid < s) red[tid] = fminf(red[tid], red[tid + s]); __syncthreads(); }
    if (tid == 0) s_wmn = red[0];
    __syncthreads();
    red[tid] = wmx; __syncthreads();
    for (int s = 128; s > 0; s >>= 1) { if (tid < s) red[tid] = fmaxf(red[tid], red[tid + s]); __syncthreads(); }
    if (tid == 0) s_wmx = red[0];
    __syncthreads();

    if (tid < 3) {
        const int bval = 2 << tid;
        const float denom = (float)((1 << bval) - 1);
        float mn = INFINITY, mx = -INFINITY; bool has = false;
        for (int nb = 0; nb < 32; ++nb) {
            if (bits[nb] == bval) { has = true; mn = fminf(mn, bmn[nb]); mx = fmaxf(mx, bmx[nb]); }
        }
        if (!has) { mn = 0.f; mx = 0.f; }
        const float scale = fmaxf((mx - mn) / denom, EPSQ);
        gstats[tid * 2 + 0] = mn;
        gstats[tid * 2 + 1] = scale;
        s_gmn[tid] = mn; s_gs[tid] = scale;
    }
    __syncthreads();

    const float wmv = s_wmn, wxv = s_wmx;

    // colJ[g][tap][co] = Σ_ci (rint((w-wm)/t) - σ)   -- same f32 div+rint as ref
    for (int idx = tid; idx < 864; idx += 256) {
        const int g   = idx / 288;
        const int rem = idx % 288;
        const int tap = rem / 32;
        const int co  = rem % 32;
        const int bval = 2 << g;
        const float denom = (float)((1 << bval) - 1);
        const float t = fmaxf((wxv - wmv) / denom, EPSQ);
        const int sig = 1 << (bval - 1);
        int sum = 0;
        for (int ci = 0; ci < 32; ++ci) {
            const int j = (int)rintf((w[co * 288 + ci * 9 + tap] - wmv) / t);
            sum += j - sig;
        }
        s_colJ[idx] = sum;
    }
    __syncthreads();

    // Tbl + coefs (f64 internally)
    for (int idx = tid; idx < 864; idx += 256) {
        const int g   = idx / 288;
        const int rem = idx % 288;
        const int cls = rem / 32;
        const int co  = rem % 32;
        const int bval = 2 << g;
        const float denom = (float)((1 << bval) - 1);
        const float t = fmaxf((wxv - wmv) / denom, EPSQ);
        const int sig = 1 << (bval - 1);
        const double A_ = (double)s_gmn[g] + (double)sig * (double)s_gs[g];
        const double B_ = (double)wmv + (double)sig * (double)t;
        const int rc = cls / 3, cc = cls % 3;
        double js = 0.0, ij = 0.0; int ninv = 0;
        for (int tap = 0; tap < 9; ++tap) {
            const int dy = tap / 3, dx = tap % 3;
            const int cj = s_colJ[g * 288 + tap * 32 + co];
            js += (double)cj;
            const bool inv = (rc == 0 && dy == 0) || (rc == 2 && dy == 2) ||
                             (cc == 0 && dx == 0) || (cc == 2 && dx == 2);
            if (inv) { ++ninv; ij += (double)cj; }
        }
        const double v = (double)t * A_ * js + 288.0 * A_ * B_ + (double)bias[co]
                       - A_ * (32.0 * B_ * (double)ninv + (double)t * ij);
        tbl[idx] = (float)v;
    }
    if (tid < 3) {
        const int bval = 2 << tid;
        const float denom = (float)((1 << bval) - 1);
        const float t = fmaxf((wxv - wmv) / denom, EPSQ);
        const int sig = 1 << (bval - 1);
        const double B_ = (double)wmv + (double)sig * (double)t;
        coefs[tid * 2 + 0] = (float)((double)s_gs[tid] * (double)t);
        coefs[tid * 2 + 1] = (float)((double)s_gs[tid] * B_);
    }

    // pack A-frags: byte (g,tap,lane,i): co=lane&31, ci=(lane>>5)*16+i, LE within u32
    for (int idx = tid; idx < 6912; idx += 256) {
        const int g     = idx / 2304;
        const int rem   = idx % 2304;
        const int tap   = rem / 256;
        const int rem2  = rem % 256;
        const int lane_ = rem2 / 4;
        const int a4    = rem2 % 4;
        const int bval = 2 << g;
        const float denom = (float)((1 << bval) - 1);
        const float t = fmaxf((wxv - wmv) / denom, EPSQ);
        const int sig = 1 << (bval - 1);
        const int co  = lane_ & 31;
        const int cib = (lane_ >> 5) * 16 + a4 * 4;
        unsigned int packed = 0;
        for (int b = 0; b < 4; ++b) {
            const int ci = cib + b;
            int jc = (int)rintf((w[co * 288 + ci * 9 + tap] - wmv) / t) - sig;
            jc = jc < -128 ? -128 : (jc > 127 ? 127 : jc);
            packed |= ((unsigned int)(unsigned char)(char)jc) << (8 * b);
        }
        wq8[idx] = packed;
    }
}

// ---------------- Kernel C: i8-MFMA conv ----------------
// grid = (6, 6, 32); block 256 (4 waves). Tile 32x32 px, all 32 co.
// LDS xkv: [34 rows][34 cols][48B ci-pitch] i8 (pitch 48 = 16-aligned, conflict-free b128).
// Wave wv owns rows wv*8..+7, processed as two 4-row quads; weights (9 A-frags) in regs.
__global__ __launch_bounds__(256, 2) void kC_conv(
    const float* __restrict__ x, const int* __restrict__ bits,
    const float* __restrict__ gstats, const float* __restrict__ coefs,
    const float* __restrict__ tbl, const unsigned int* __restrict__ wq8,
    float* __restrict__ out)
{
    __shared__ v4i   xkv[34 * 34 * 3];   // 55488 B
    __shared__ int   cs2[34 * 34];       // 4624 B : per-pixel Σ_ci kc
    __shared__ float tlds[288];          // 1152 B : Tbl for this g

    const int n  = blockIdx.z;
    const int oy = blockIdx.y * 32;
    const int ox = blockIdx.x * 32;
    const int tid  = threadIdx.x;
    const int lane = tid & 63;
    const int wv   = tid >> 6;

    const int bval = bits[n];
    const int g = (bval == 2) ? 0 : (bval == 4 ? 1 : 2);
    const int sig = 1 << (bval - 1);
    const float mn = gstats[g * 2 + 0];
    const float s  = gstats[g * 2 + 1];
    const float C1 = coefs[g * 2 + 0];
    const float C2 = coefs[g * 2 + 1];

    // weights -> registers (9 A-frags)
    const v4i* wA = (const v4i*)(wq8 + (size_t)g * 2304);   // g*9216 bytes
    v4i wfr[9];
#pragma unroll
    for (int t = 0; t < 9; ++t) wfr[t] = wA[t * 64 + lane];

    for (int i = tid; i < 288; i += 256) tlds[i] = tbl[g * 288 + i];

    // ---- stage: quantize to centered i8 codes (pad -> 0) ----
    const float* xn = x + (size_t)n * 1179648;
    char* xk = (char*)xkv;
    for (int idx = tid; idx < 36992; idx += 256) {
        const int ci  = idx / 1156;
        const int rem = idx - ci * 1156;
        const int r   = rem / 34;
        const int c   = rem - r * 34;
        const int gy = oy + r - 1, gx = ox + c - 1;
        int kq = 0;
        if ((unsigned)gy < 192u && (unsigned)gx < 192u) {
            const float v = xn[((size_t)ci * 192 + gy) * 192 + gx];
            const float d = (v - mn) / s;            // IEEE div: matches ref boundaries
            kq = (int)rintf(d) - sig;
            kq = kq < -128 ? -128 : (kq > 127 ? 127 : kq);
        }
        xk[(r * 34 + c) * 48 + ci] = (char)kq;
    }
    __syncthreads();

    // ---- per-pixel ci-sums ----
    for (int idx = tid; idx < 1156; idx += 256) {
        const v4i lo = xkv[idx * 3 + 0];
        const v4i hi = xkv[idx * 3 + 1];
        cs2[idx] = bytesum4(lo.x) + bytesum4(lo.y) + bytesum4(lo.z) + bytesum4(lo.w)
                 + bytesum4(hi.x) + bytesum4(hi.y) + bytesum4(hi.z) + bytesum4(hi.w);
    }
    __syncthreads();

    // ---- main: MFMA conv + epilogue ----
    const int c  = lane & 31;           // px col within tile; also B-frag col
    const int ch = lane >> 5;           // ci half
    const int gx = ox + c;
    const int cc = (gx == 0) ? 0 : ((gx == 191) ? 2 : 1);

    for (int q = 0; q < 2; ++q) {
        const int r0 = wv * 8 + q * 4;
        v16i acc[4] = {};
#pragma unroll
        for (int dyr = 0; dyr < 6; ++dyr) {
            const int xrow = r0 + dyr;
            const v4i bf0 = xkv[(xrow * 34 + c + 0) * 3 + ch];
            const v4i bf1 = xkv[(xrow * 34 + c + 1) * 3 + ch];
            const v4i bf2 = xkv[(xrow * 34 + c + 2) * 3 + ch];
#pragma unroll
            for (int m = 0; m < 4; ++m) {
                const int dy = dyr - m;
                if (dy >= 0 && dy < 3) {
                    acc[m] = __builtin_amdgcn_mfma_i32_32x32x32_i8(wfr[dy * 3 + 0], bf0, acc[m], 0, 0, 0);
                    acc[m] = __builtin_amdgcn_mfma_i32_32x32x32_i8(wfr[dy * 3 + 1], bf1, acc[m], 0, 0, 0);
                    acc[m] = __builtin_amdgcn_mfma_i32_32x32x32_i8(wfr[dy * 3 + 2], bf2, acc[m], 0, 0, 0);
                }
            }
        }
#pragma unroll
        for (int m = 0; m < 4; ++m) {
            const int r  = r0 + m;
            const int gy = oy + r;
            int k1 = 0;
#pragma unroll
            for (int dy = 0; dy < 3; ++dy)
#pragma unroll
                for (int dx = 0; dx < 3; ++dx)
                    k1 += cs2[(r + dy) * 34 + (c + dx)];
            const int rc = (gy == 0) ? 0 : ((gy == 191) ? 2 : 1);
            const int cls = rc * 3 + cc;
            const float t2 = C2 * (float)k1;
#pragma unroll
            for (int reg = 0; reg < 16; ++reg) {
                const int co = (reg & 3) + 8 * (reg >> 2) + 4 * ch;
                const float y = fmaf(C1, (float)acc[m][reg], t2 + tlds[cls * 32 + co]);
                out[(((size_t)n * 32 + co) * 192 + gy) * 192 + gx] = y;
            }
        }
    }
}

extern "C" void kernel_launch(void* const* d_in, const int* in_sizes, int n_in,
                              void* d_out, int out_size, void* d_ws, size_t ws_size,
                              hipStream_t stream) {
    const float* x      = (const float*)d_in[0];
    const float* weight = (const float*)d_in[1];
    const float* bias   = (const float*)d_in[2];
    const int*   bits   = (const int*)d_in[3];
    float* out = (float*)d_out;

    float* ws       = (float*)d_ws;
    float* partials = ws;                         // 2304 floats
    float* gstats   = ws + 2304;                  // 8
    float* coefs    = ws + 2312;                  // 8
    float* tbl      = ws + 2320;                  // 864
    unsigned int* wq8 = (unsigned int*)(ws + 3184); // 6912 u32 (byte off 12736, 16-aligned)

    kA_partial_minmax<<<32 * 36, 256, 0, stream>>>(x, partials);
    kB_stats_and_wq<<<1, 256, 0, stream>>>(weight, bias, bits, partials, gstats, coefs, tbl, wq8);

    dim3 grid(6, 6, 32);
    kC_conv<<<grid, 256, 0, stream>>>(x, bits, gstats, coefs, tbl, wq8, out);
}

// Round 6
// 168.357 us; speedup vs baseline: 2.7379x; 1.9913x over previous
//
#include <hip/hip_runtime.h>

#define EPSQ 1e-8f

typedef int v4i  __attribute__((ext_vector_type(4)));
typedef int v16i __attribute__((ext_vector_type(16)));

// x: (32, 32, 192, 192) f32; weight: (32, 32, 3, 3) f32; bias: (32,) f32; bits: (32,) i32
//
// Integer-exact decomposition (per batch n with group g, σ=2^(b-1)):
//   x_q = mn + s·k,  w_q = wm + t·j,  kc = k−σ, jc = j−σ  (i8, centered; k,j ∈ [0,2^b−1] guaranteed)
//   y[p,co] = s·t·KJ[p,co] + s·(wm+σt)·K1[p] + Tbl[class(p)][co]
//   KJ = Σ_{taps,ci} kc·jc  (i8 MFMA, exact i32; pad kc=0)
//   K1 = Σ_{taps,ci} kc     (box sum of per-pixel ci-sums; pad 0)
// k and j use the same IEEE f32 div + rintf as the reference → identical quant decisions.

__device__ __forceinline__ int bytesum4(int v) {
#if __has_builtin(__builtin_amdgcn_sdot4)
    return __builtin_amdgcn_sdot4(v, 0x01010101, 0, false);
#else
    return (int)(char)(v) + (int)(char)(v >> 8) + (int)(char)(v >> 16) + (int)(char)(v >> 24);
#endif
}

// ---------------- Kernel A: per-(batch, chunk) min/max partials ----------------
__global__ __launch_bounds__(256) void kA_partial_minmax(
    const float* __restrict__ x, float* __restrict__ partials)
{
    const int batch = blockIdx.x / 36;
    const int blk   = blockIdx.x % 36;
    const float* xb = x + (size_t)batch * 1179648 + (size_t)blk * 32768;
    float mn = INFINITY, mx = -INFINITY;
#pragma unroll
    for (int i = 0; i < 32; ++i) {
        const float4 v = reinterpret_cast<const float4*>(xb)[i * 256 + threadIdx.x];
        mn = fminf(mn, fminf(fminf(v.x, v.y), fminf(v.z, v.w)));
        mx = fmaxf(mx, fmaxf(fmaxf(v.x, v.y), fmaxf(v.z, v.w)));
    }
    __shared__ float smn[256], smx[256];
    smn[threadIdx.x] = mn; smx[threadIdx.x] = mx;
    __syncthreads();
    for (int s = 128; s > 0; s >>= 1) {
        if (threadIdx.x < s) {
            smn[threadIdx.x] = fminf(smn[threadIdx.x], smn[threadIdx.x + s]);
            smx[threadIdx.x] = fmaxf(smx[threadIdx.x], smx[threadIdx.x + s]);
        }
        __syncthreads();
    }
    if (threadIdx.x == 0) {
        partials[blockIdx.x * 2 + 0] = smn[0];
        partials[blockIdx.x * 2 + 1] = smx[0];
    }
}

// ---------------- Kernel B: stats, tables, packed i8 weights ----------------
// gstats[g*2+{0,1}] = mn_g, s_g
// coefs[g*2+{0,1}]  = C1 = s·t, C2 = s·(wm+σt)
// tbl[g*288 + cls*32 + co]
// wq8[((g*9+tap)*64+lane)*4 + a4] : A-frag words; lane: co=lane&31, ci=(lane>>5)*16+4*a4+b
__global__ __launch_bounds__(256) void kB_stats_and_wq(
    const float* __restrict__ w, const float* __restrict__ bias,
    const int* __restrict__ bits, const float* __restrict__ partials,
    float* __restrict__ gstats, float* __restrict__ coefs,
    float* __restrict__ tbl, unsigned int* __restrict__ wq8)
{
    __shared__ float bmn[32], bmx[32];
    __shared__ float red[256];
    __shared__ float s_wmn, s_wmx;
    __shared__ float s_gmn[3], s_gs[3];
    __shared__ int   s_colJ[864];          // [g][tap][co] = Σ_ci jc
    const int tid = threadIdx.x;

    if (tid < 32) {
        float mn = INFINITY, mx = -INFINITY;
        for (int i = 0; i < 36; ++i) {
            mn = fminf(mn, partials[(tid * 36 + i) * 2 + 0]);
            mx = fmaxf(mx, partials[(tid * 36 + i) * 2 + 1]);
        }
        bmn[tid] = mn; bmx[tid] = mx;
    }

    float wmn = INFINITY, wmx = -INFINITY;
    for (int i = tid; i < 9216; i += 256) {
        const float v = w[i];
        wmn = fminf(wmn, v); wmx = fmaxf(wmx, v);
    }
    red[tid] = wmn; __syncthreads();
    for (int s = 128; s > 0; s >>= 1) { if (tid < s) red[tid] = fminf(red[tid], red[tid + s]); __syncthreads(); }
    if (tid == 0) s_wmn = red[0];
    __syncthreads();
    red[tid] = wmx; __syncthreads();
    for (int s = 128; s > 0; s >>= 1) { if (tid < s) red[tid] = fmaxf(red[tid], red[tid + s]); __syncthreads(); }
    if (tid == 0) s_wmx = red[0];
    __syncthreads();

    if (tid < 3) {
        const int bval = 2 << tid;
        const float denom = (float)((1 << bval) - 1);
        float mn = INFINITY, mx = -INFINITY; bool has = false;
        for (int nb = 0; nb < 32; ++nb) {
            if (bits[nb] == bval) { has = true; mn = fminf(mn, bmn[nb]); mx = fmaxf(mx, bmx[nb]); }
        }
        if (!has) { mn = 0.f; mx = 0.f; }
        const float scale = fmaxf((mx - mn) / denom, EPSQ);
        gstats[tid * 2 + 0] = mn;
        gstats[tid * 2 + 1] = scale;
        s_gmn[tid] = mn; s_gs[tid] = scale;
    }
    __syncthreads();

    const float wmv = s_wmn, wxv = s_wmx;

    // colJ[g][tap][co] = Σ_ci (rint((w-wm)/t) - σ)   -- same f32 div+rint as ref
    for (int idx = tid; idx < 864; idx += 256) {
        const int g   = idx / 288;
        const int rem = idx % 288;
        const int tap = rem / 32;
        const int co  = rem % 32;
        const int bval = 2 << g;
        const float denom = (float)((1 << bval) - 1);
        const float t = fmaxf((wxv - wmv) / denom, EPSQ);
        const int sig = 1 << (bval - 1);
        int sum = 0;
        for (int ci = 0; ci < 32; ++ci) {
            const int j = (int)rintf((w[co * 288 + ci * 9 + tap] - wmv) / t);
            sum += j - sig;
        }
        s_colJ[idx] = sum;
    }
    __syncthreads();

    // Tbl + coefs (f64 internally)
    for (int idx = tid; idx < 864; idx += 256) {
        const int g   = idx / 288;
        const int rem = idx % 288;
        const int cls = rem / 32;
        const int co  = rem % 32;
        const int bval = 2 << g;
        const float denom = (float)((1 << bval) - 1);
        const float t = fmaxf((wxv - wmv) / denom, EPSQ);
        const int sig = 1 << (bval - 1);
        const double A_ = (double)s_gmn[g] + (double)sig * (double)s_gs[g];
        const double B_ = (double)wmv + (double)sig * (double)t;
        const int rc = cls / 3, cc = cls % 3;
        double js = 0.0, ij = 0.0; int ninv = 0;
        for (int tap = 0; tap < 9; ++tap) {
            const int dy = tap / 3, dx = tap % 3;
            const int cj = s_colJ[g * 288 + tap * 32 + co];
            js += (double)cj;
            const bool inv = (rc == 0 && dy == 0) || (rc == 2 && dy == 2) ||
                             (cc == 0 && dx == 0) || (cc == 2 && dx == 2);
            if (inv) { ++ninv; ij += (double)cj; }
        }
        const double v = (double)t * A_ * js + 288.0 * A_ * B_ + (double)bias[co]
                       - A_ * (32.0 * B_ * (double)ninv + (double)t * ij);
        tbl[idx] = (float)v;
    }
    if (tid < 3) {
        const int bval = 2 << tid;
        const float denom = (float)((1 << bval) - 1);
        const float t = fmaxf((wxv - wmv) / denom, EPSQ);
        const int sig = 1 << (bval - 1);
        const double B_ = (double)wmv + (double)sig * (double)t;
        coefs[tid * 2 + 0] = (float)((double)s_gs[tid] * (double)t);
        coefs[tid * 2 + 1] = (float)((double)s_gs[tid] * B_);
    }

    // pack A-frags: byte (g,tap,lane,i): co=lane&31, ci=(lane>>5)*16+i, LE within u32
    for (int idx = tid; idx < 6912; idx += 256) {
        const int g     = idx / 2304;
        const int rem   = idx % 2304;
        const int tap   = rem / 256;
        const int rem2  = rem % 256;
        const int lane_ = rem2 / 4;
        const int a4    = rem2 % 4;
        const int bval = 2 << g;
        const float denom = (float)((1 << bval) - 1);
        const float t = fmaxf((wxv - wmv) / denom, EPSQ);
        const int sig = 1 << (bval - 1);
        const int co  = lane_ & 31;
        const int cib = (lane_ >> 5) * 16 + a4 * 4;
        unsigned int packed = 0;
        for (int b = 0; b < 4; ++b) {
            const int ci = cib + b;
            int jc = (int)rintf((w[co * 288 + ci * 9 + tap] - wmv) / t) - sig;
            jc = jc < -128 ? -128 : (jc > 127 ? 127 : jc);
            packed |= ((unsigned int)(unsigned char)(char)jc) << (8 * b);
        }
        wq8[idx] = packed;
    }
}

// ---------------- Kernel C: i8-MFMA conv ----------------
// grid = (6, 12, 32); block 256 (4 waves). Tile 16 rows x 32 cols, all 32 co.
// LDS xkv: [18 rows][34 cols][48B ci-pitch] i8 -> 29.4 KB; total ~33 KB -> 4 blocks/CU.
// VGPR cap 128 via launch_bounds(256,4) -> 16 waves/CU.
// Wave wv owns output rows wv*4..+3 (one quad); weights (9 A-frags) register-resident.
__global__ __launch_bounds__(256, 4) void kC_conv(
    const float* __restrict__ x, const int* __restrict__ bits,
    const float* __restrict__ gstats, const float* __restrict__ coefs,
    const float* __restrict__ tbl, const unsigned int* __restrict__ wq8,
    float* __restrict__ out)
{
    __shared__ v4i   xkv[18 * 34 * 3];   // 29376 B : centered i8 codes [row][col][48B]
    __shared__ int   cs2[18 * 34];       // 2448 B  : per-pixel Σ_ci kc
    __shared__ float tlds[288];          // 1152 B  : Tbl for this g

    const int n  = blockIdx.z;
    const int oy = blockIdx.y * 16;
    const int ox = blockIdx.x * 32;
    const int tid  = threadIdx.x;
    const int lane = tid & 63;
    const int wv   = tid >> 6;

    const int bval = bits[n];
    const int g = (bval == 2) ? 0 : (bval == 4 ? 1 : 2);
    const int sig = 1 << (bval - 1);
    const float mn = gstats[g * 2 + 0];
    const float s  = gstats[g * 2 + 1];
    const float C1 = coefs[g * 2 + 0];
    const float C2 = coefs[g * 2 + 1];

    // weights -> registers (9 A-frags)
    const v4i* wA = (const v4i*)(wq8 + (size_t)g * 2304);
    v4i wfr[9];
#pragma unroll
    for (int t = 0; t < 9; ++t) wfr[t] = wA[t * 64 + lane];

    for (int i = tid; i < 288; i += 256) tlds[i] = tbl[g * 288 + i];

    // ---- stage: quantize to centered i8 codes, 4 ci-planes per unit (pad -> 0) ----
    const float* xn = x + (size_t)n * 1179648;
    char* xk = (char*)xkv;
    for (int u = tid; u < 4896; u += 256) {          // 8 ci-quads x 612 px
        const int ci4 = u / 612;
        const int px  = u - ci4 * 612;
        const int r   = px / 34;
        const int c   = px - r * 34;
        const int gy = oy + r - 1, gx = ox + c - 1;
        unsigned int packed = 0;
        if ((unsigned)gy < 192u && (unsigned)gx < 192u) {
            const size_t base = ((size_t)(ci4 * 4) * 192 + gy) * 192 + gx;
            const float v0 = xn[base];
            const float v1 = xn[base + 36864];
            const float v2 = xn[base + 73728];
            const float v3 = xn[base + 110592];
            // IEEE f32 div + rintf: identical quant decisions to reference
            const int k0 = (int)rintf((v0 - mn) / s) - sig;
            const int k1 = (int)rintf((v1 - mn) / s) - sig;
            const int k2 = (int)rintf((v2 - mn) / s) - sig;
            const int k3 = (int)rintf((v3 - mn) / s) - sig;
            packed = (unsigned int)(unsigned char)(char)k0
                   | ((unsigned int)(unsigned char)(char)k1 << 8)
                   | ((unsigned int)(unsigned char)(char)k2 << 16)
                   | ((unsigned int)(unsigned char)(char)k3 << 24);
        }
        *(unsigned int*)(xk + px * 48 + ci4 * 4) = packed;
    }
    __syncthreads();

    // ---- per-pixel ci-sums ----
    for (int idx = tid; idx < 612; idx += 256) {
        const v4i lo = xkv[idx * 3 + 0];
        const v4i hi = xkv[idx * 3 + 1];
        cs2[idx] = bytesum4(lo.x) + bytesum4(lo.y) + bytesum4(lo.z) + bytesum4(lo.w)
                 + bytesum4(hi.x) + bytesum4(hi.y) + bytesum4(hi.z) + bytesum4(hi.w);
    }
    __syncthreads();

    // ---- main: MFMA conv + epilogue (one 4-row quad per wave) ----
    const int c  = lane & 31;           // px col within tile; also B-frag col
    const int ch = lane >> 5;           // ci half
    const int gx = ox + c;
    const int cc = (gx == 0) ? 0 : ((gx == 191) ? 2 : 1);
    const int r0 = wv * 4;

    v16i acc[4] = {};
#pragma unroll
    for (int dyr = 0; dyr < 6; ++dyr) {
        const int xrow = r0 + dyr;                   // rows r0..r0+5 (max 17)
        const v4i bf0 = xkv[(xrow * 34 + c + 0) * 3 + ch];
        const v4i bf1 = xkv[(xrow * 34 + c + 1) * 3 + ch];
        const v4i bf2 = xkv[(xrow * 34 + c + 2) * 3 + ch];
#pragma unroll
        for (int m = 0; m < 4; ++m) {
            const int dy = dyr - m;
            if (dy >= 0 && dy < 3) {
                acc[m] = __builtin_amdgcn_mfma_i32_32x32x32_i8(wfr[dy * 3 + 0], bf0, acc[m], 0, 0, 0);
                acc[m] = __builtin_amdgcn_mfma_i32_32x32x32_i8(wfr[dy * 3 + 1], bf1, acc[m], 0, 0, 0);
                acc[m] = __builtin_amdgcn_mfma_i32_32x32x32_i8(wfr[dy * 3 + 2], bf2, acc[m], 0, 0, 0);
            }
        }
    }

#pragma unroll
    for (int m = 0; m < 4; ++m) {
        const int r  = r0 + m;
        const int gy = oy + r;
        int k1 = 0;
#pragma unroll
        for (int dy = 0; dy < 3; ++dy)
#pragma unroll
            for (int dx = 0; dx < 3; ++dx)
                k1 += cs2[(r + dy) * 34 + (c + dx)];
        const int rc = (gy == 0) ? 0 : ((gy == 191) ? 2 : 1);
        const int cls = rc * 3 + cc;
        const float t2 = C2 * (float)k1;
#pragma unroll
        for (int reg = 0; reg < 16; ++reg) {
            const int co = (reg & 3) + 8 * (reg >> 2) + 4 * ch;
            const float y = fmaf(C1, (float)acc[m][reg], t2 + tlds[cls * 32 + co]);
            out[(((size_t)n * 32 + co) * 192 + gy) * 192 + gx] = y;
        }
    }
}

extern "C" void kernel_launch(void* const* d_in, const int* in_sizes, int n_in,
                              void* d_out, int out_size, void* d_ws, size_t ws_size,
                              hipStream_t stream) {
    const float* x      = (const float*)d_in[0];
    const float* weight = (const float*)d_in[1];
    const float* bias   = (const float*)d_in[2];
    const int*   bits   = (const int*)d_in[3];
    float* out = (float*)d_out;

    float* ws       = (float*)d_ws;
    float* partials = ws;                           // 2304 floats
    float* gstats   = ws + 2304;                    // 8
    float* coefs    = ws + 2312;                    // 8
    float* tbl      = ws + 2320;                    // 864
    unsigned int* wq8 = (unsigned int*)(ws + 3184); // 6912 u32 (byte off 12736, 16-aligned)

    kA_partial_minmax<<<32 * 36, 256, 0, stream>>>(x, partials);
    kB_stats_and_wq<<<1, 256, 0, stream>>>(weight, bias, bits, partials, gstats, coefs, tbl, wq8);

    dim3 grid(6, 12, 32);
    kC_conv<<<grid, 256, 0, stream>>>(x, bits, gstats, coefs, tbl, wq8, out);
}

// Round 7
// 146.618 us; speedup vs baseline: 3.1439x; 1.1483x over previous
//
#include <hip/hip_runtime.h>

#define EPSQ 1e-8f

typedef int v4i  __attribute__((ext_vector_type(4)));
typedef int v16i __attribute__((ext_vector_type(16)));

// x: (32, 32, 192, 192) f32; weight: (32, 32, 3, 3) f32; bias: (32,) f32; bits: (32,) i32
//
// Integer-exact decomposition (per batch n with group g, σ=2^(b-1)):
//   x_q = mn + s·k,  w_q = wm + t·j,  kc = k−σ, jc = j−σ  (i8, centered; ranges fit i8 for b≤8)
//   y[p,co] = s·t·KJ[p,co] + s·(wm+σt)·K1[p] + Tbl[class(p)][co]
//   KJ = Σ_{taps,ci} kc·jc  (i8 MFMA, exact i32; pad kc=0)
//   K1 = Σ_{taps,ci} kc     (box sum of per-pixel ci-sums; pad 0)
// k and j use the same IEEE f32 div + rintf as the reference → identical quant decisions.

// ---------------- Kernel A: per-(batch, chunk) min/max partials ----------------
__global__ __launch_bounds__(256) void kA_partial_minmax(
    const float* __restrict__ x, float* __restrict__ partials)
{
    const int batch = blockIdx.x / 36;
    const int blk   = blockIdx.x % 36;
    const float* xb = x + (size_t)batch * 1179648 + (size_t)blk * 32768;
    float mn = INFINITY, mx = -INFINITY;
#pragma unroll
    for (int i = 0; i < 32; ++i) {
        const float4 v = reinterpret_cast<const float4*>(xb)[i * 256 + threadIdx.x];
        mn = fminf(mn, fminf(fminf(v.x, v.y), fminf(v.z, v.w)));
        mx = fmaxf(mx, fmaxf(fmaxf(v.x, v.y), fmaxf(v.z, v.w)));
    }
    __shared__ float smn[256], smx[256];
    smn[threadIdx.x] = mn; smx[threadIdx.x] = mx;
    __syncthreads();
    for (int s = 128; s > 0; s >>= 1) {
        if (threadIdx.x < s) {
            smn[threadIdx.x] = fminf(smn[threadIdx.x], smn[threadIdx.x + s]);
            smx[threadIdx.x] = fmaxf(smx[threadIdx.x], smx[threadIdx.x + s]);
        }
        __syncthreads();
    }
    if (threadIdx.x == 0) {
        partials[blockIdx.x * 2 + 0] = smn[0];
        partials[blockIdx.x * 2 + 1] = smx[0];
    }
}

// ---------------- Kernel W: weight codes (27 blocks, one per (g,tap)) ----------------
// wq8[((g*9+tap)*64+lane)*4 + a4] : A-frag words; byte i of word: co=lane&31, ci=(lane>>5)*16+a4*4+i
// colJ[g*288 + tap*32 + co] = Σ_ci jc
__global__ __launch_bounds__(256) void kW_weights(
    const float* __restrict__ w, unsigned int* __restrict__ wq8,
    int* __restrict__ colJ)
{
    __shared__ float red[256];
    __shared__ float s_wmn, s_wmx;
    __shared__ int   jred[256];
    const int tid = threadIdx.x;
    const int g   = blockIdx.x / 9;
    const int tap = blockIdx.x % 9;

    float wmn = INFINITY, wmx = -INFINITY;
    for (int i = tid; i < 9216; i += 256) {
        const float v = w[i];
        wmn = fminf(wmn, v); wmx = fmaxf(wmx, v);
    }
    red[tid] = wmn; __syncthreads();
    for (int s = 128; s > 0; s >>= 1) { if (tid < s) red[tid] = fminf(red[tid], red[tid + s]); __syncthreads(); }
    if (tid == 0) s_wmn = red[0];
    __syncthreads();
    red[tid] = wmx; __syncthreads();
    for (int s = 128; s > 0; s >>= 1) { if (tid < s) red[tid] = fmaxf(red[tid], red[tid + s]); __syncthreads(); }
    if (tid == 0) s_wmx = red[0];
    __syncthreads();

    const float wmv = s_wmn, wxv = s_wmx;
    const int bval = 2 << g;
    const float denom = (float)((1 << bval) - 1);
    const float t = fmaxf((wxv - wmv) / denom, EPSQ);
    const int sig = 1 << (bval - 1);

    const int co = tid & 31;
    const int q  = tid >> 5;          // ci-quad 0..7
    unsigned int packed = 0;
    int jsum = 0;
#pragma unroll
    for (int b = 0; b < 4; ++b) {
        const int ci = q * 4 + b;
        int jc = (int)rintf((w[co * 288 + ci * 9 + tap] - wmv) / t) - sig;  // IEEE div, as ref
        jc = jc < -128 ? -128 : (jc > 127 ? 127 : jc);                     // no-op for b<=8
        jsum += jc;
        packed |= ((unsigned int)(unsigned char)(char)jc) << (8 * b);
    }
    const int lane_ = (q >> 2) * 32 + co;
    const int a4    = q & 3;
    wq8[((size_t)(g * 9 + tap) * 64 + lane_) * 4 + a4] = packed;

    jred[tid] = jsum; __syncthreads();
    if (tid < 128) jred[tid] += jred[tid + 128];
    __syncthreads();
    if (tid < 64) jred[tid] += jred[tid + 64];
    __syncthreads();
    if (tid < 32) colJ[g * 288 + tap * 32 + tid] = jred[tid] + jred[tid + 32];
}

// ---------------- Kernel B2: group stats + coefs + Tbl (1 block) ----------------
// gstats[g*2+{0,1}] = mn_g, s_g ; coefs[g*2+{0,1}] = s·t, s·(wm+σt) ; tbl[g*288+cls*32+co]
__global__ __launch_bounds__(256) void kB2_stats_tbl(
    const float* __restrict__ w, const float* __restrict__ bias,
    const int* __restrict__ bits, const float* __restrict__ partials,
    const int* __restrict__ colJ,
    float* __restrict__ gstats, float* __restrict__ coefs, float* __restrict__ tbl)
{
    __shared__ float bmn[32], bmx[32];
    __shared__ float red[256];
    __shared__ float s_wmn, s_wmx;
    __shared__ float s_gmn[3], s_gs[3];
    const int tid = threadIdx.x;

    if (tid < 32) {
        float mn = INFINITY, mx = -INFINITY;
        for (int i = 0; i < 36; ++i) {
            mn = fminf(mn, partials[(tid * 36 + i) * 2 + 0]);
            mx = fmaxf(mx, partials[(tid * 36 + i) * 2 + 1]);
        }
        bmn[tid] = mn; bmx[tid] = mx;
    }

    float wmn = INFINITY, wmx = -INFINITY;
    for (int i = tid; i < 9216; i += 256) {
        const float v = w[i];
        wmn = fminf(wmn, v); wmx = fmaxf(wmx, v);
    }
    red[tid] = wmn; __syncthreads();
    for (int s = 128; s > 0; s >>= 1) { if (tid < s) red[tid] = fminf(red[tid], red[tid + s]); __syncthreads(); }
    if (tid == 0) s_wmn = red[0];
    __syncthreads();
    red[tid] = wmx; __syncthreads();
    for (int s = 128; s > 0; s >>= 1) { if (tid < s) red[tid] = fmaxf(red[tid], red[tid + s]); __syncthreads(); }
    if (tid == 0) s_wmx = red[0];
    __syncthreads();

    if (tid < 3) {
        const int bval = 2 << tid;
        const float denom = (float)((1 << bval) - 1);
        float mn = INFINITY, mx = -INFINITY; bool has = false;
        for (int nb = 0; nb < 32; ++nb) {
            if (bits[nb] == bval) { has = true; mn = fminf(mn, bmn[nb]); mx = fmaxf(mx, bmx[nb]); }
        }
        if (!has) { mn = 0.f; mx = 0.f; }
        const float scale = fmaxf((mx - mn) / denom, EPSQ);
        gstats[tid * 2 + 0] = mn;
        gstats[tid * 2 + 1] = scale;
        s_gmn[tid] = mn; s_gs[tid] = scale;

        const float t = fmaxf((s_wmx - s_wmn) / denom, EPSQ);
        const int sig = 1 << (bval - 1);
        const double B_ = (double)s_wmn + (double)sig * (double)t;
        coefs[tid * 2 + 0] = (float)((double)scale * (double)t);
        coefs[tid * 2 + 1] = (float)((double)scale * B_);
    }
    __syncthreads();

    const float wmv = s_wmn, wxv = s_wmx;
    for (int idx = tid; idx < 864; idx += 256) {
        const int g   = idx / 288;
        const int rem = idx % 288;
        const int cls = rem / 32;
        const int co  = rem % 32;
        const int bval = 2 << g;
        const float denom = (float)((1 << bval) - 1);
        const float t = fmaxf((wxv - wmv) / denom, EPSQ);
        const int sig = 1 << (bval - 1);
        const double A_ = (double)s_gmn[g] + (double)sig * (double)s_gs[g];
        const double B_ = (double)wmv + (double)sig * (double)t;
        const int rc = cls / 3, cc = cls % 3;
        double js = 0.0, ij = 0.0; int ninv = 0;
        for (int tap = 0; tap < 9; ++tap) {
            const int dy = tap / 3, dx = tap % 3;
            const int cj = colJ[g * 288 + tap * 32 + co];
            js += (double)cj;
            const bool inv = (rc == 0 && dy == 0) || (rc == 2 && dy == 2) ||
                             (cc == 0 && dx == 0) || (cc == 2 && dx == 2);
            if (inv) { ++ninv; ij += (double)cj; }
        }
        const double v = (double)t * A_ * js + 288.0 * A_ * B_ + (double)bias[co]
                       - A_ * (32.0 * B_ * (double)ninv + (double)t * ij);
        tbl[idx] = (float)v;
    }
}

// ---------------- Kernel C: i8-MFMA conv ----------------
// grid = (6, 12, 32); block 256 (4 waves). Tile 16 rows x 32 cols, all 32 co.
// LDS xkv: [18 rows][34 cols][48B ci-pitch] i8 (29376 B) + cs2 i16 (1224) + tlds (1152).
// Staging: thread-per-pixel, 32-deep load MLP, 2 conflict-free ds_write_b128/px,
// per-pixel ci-sum computed in-register (no second pass).
__global__ __launch_bounds__(256, 4) void kC_conv(
    const float* __restrict__ x, const int* __restrict__ bits,
    const float* __restrict__ gstats, const float* __restrict__ coefs,
    const float* __restrict__ tbl, const unsigned int* __restrict__ wq8,
    float* __restrict__ out)
{
    __shared__ v4i   xkv[18 * 34 * 3];   // 29376 B : centered i8 codes [px][48B]
    __shared__ short cs2s[18 * 34];      // 1224 B  : per-pixel Σ_ci kc
    __shared__ float tlds[288];          // 1152 B  : Tbl for this g

    const int n  = blockIdx.z;
    const int oy = blockIdx.y * 16;
    const int ox = blockIdx.x * 32;
    const int tid  = threadIdx.x;
    const int lane = tid & 63;
    const int wv   = tid >> 6;

    const int bval = bits[n];
    const int g = (bval == 2) ? 0 : (bval == 4 ? 1 : 2);
    const int sig = 1 << (bval - 1);
    const float mn = gstats[g * 2 + 0];
    const float s  = gstats[g * 2 + 1];
    const float C1 = coefs[g * 2 + 0];
    const float C2 = coefs[g * 2 + 1];

    // weights -> registers (9 A-frags)
    const v4i* wA = (const v4i*)(wq8 + (size_t)g * 2304);
    v4i wfr[9];
#pragma unroll
    for (int t = 0; t < 9; ++t) wfr[t] = wA[t * 64 + lane];

    for (int i = tid; i < 288; i += 256) tlds[i] = tbl[g * 288 + i];

    // ---- stage: quantize all 32 ci for one pixel per thread (pad -> 0) ----
    const float* xn = x + (size_t)n * 1179648;
    char* xk = (char*)xkv;
    for (int px = tid; px < 612; px += 256) {
        const int r = px / 34;
        const int c = px - r * 34;
        const int gy = oy + r - 1, gx = ox + c - 1;
        const bool valid = ((unsigned)gy < 192u) && ((unsigned)gx < 192u);
        const float* xp = xn + (size_t)(valid ? gy : 0) * 192 + (valid ? gx : 0);
        int ksum = 0;
        v4i pk0, pk1;
#pragma unroll
        for (int h = 0; h < 2; ++h) {
            float v[16];
#pragma unroll
            for (int i = 0; i < 16; ++i) v[i] = xp[(size_t)(h * 16 + i) * 36864];
            int w4[4];
#pragma unroll
            for (int q4 = 0; q4 < 4; ++q4) {
                unsigned int pw = 0;
#pragma unroll
                for (int b = 0; b < 4; ++b) {
                    // IEEE f32 div + rintf: identical quant decisions to reference
                    int kq = (int)rintf((v[q4 * 4 + b] - mn) / s) - sig;
                    kq = kq < -128 ? -128 : (kq > 127 ? 127 : kq);   // no-op for b<=8
                    ksum += kq;
                    pw |= ((unsigned int)(unsigned char)(char)kq) << (8 * b);
                }
                w4[q4] = (int)pw;
            }
            if (h == 0) pk0 = (v4i){w4[0], w4[1], w4[2], w4[3]};
            else        pk1 = (v4i){w4[0], w4[1], w4[2], w4[3]};
        }
        if (!valid) { pk0 = (v4i){0,0,0,0}; pk1 = (v4i){0,0,0,0}; ksum = 0; }
        *(v4i*)(xk + px * 48 +  0) = pk0;
        *(v4i*)(xk + px * 48 + 16) = pk1;
        cs2s[px] = (short)ksum;
    }
    __syncthreads();

    // ---- main: MFMA conv + epilogue (one 4-row quad per wave) ----
    const int c  = lane & 31;           // px col within tile; also B-frag col
    const int ch = lane >> 5;           // ci half
    const int gx = ox + c;
    const int cc = (gx == 0) ? 0 : ((gx == 191) ? 2 : 1);
    const int r0 = wv * 4;

    v16i acc[4] = {};
#pragma unroll
    for (int dyr = 0; dyr < 6; ++dyr) {
        const int xrow = r0 + dyr;                   // rows r0..r0+5 (max 17)
        const v4i bf0 = xkv[(xrow * 34 + c + 0) * 3 + ch];
        const v4i bf1 = xkv[(xrow * 34 + c + 1) * 3 + ch];
        const v4i bf2 = xkv[(xrow * 34 + c + 2) * 3 + ch];
#pragma unroll
        for (int m = 0; m < 4; ++m) {
            const int dy = dyr - m;
            if (dy >= 0 && dy < 3) {
                acc[m] = __builtin_amdgcn_mfma_i32_32x32x32_i8(wfr[dy * 3 + 0], bf0, acc[m], 0, 0, 0);
                acc[m] = __builtin_amdgcn_mfma_i32_32x32x32_i8(wfr[dy * 3 + 1], bf1, acc[m], 0, 0, 0);
                acc[m] = __builtin_amdgcn_mfma_i32_32x32x32_i8(wfr[dy * 3 + 2], bf2, acc[m], 0, 0, 0);
            }
        }
    }

#pragma unroll
    for (int m = 0; m < 4; ++m) {
        const int r  = r0 + m;
        const int gy = oy + r;
        int k1 = 0;
#pragma unroll
        for (int dy = 0; dy < 3; ++dy)
#pragma unroll
            for (int dx = 0; dx < 3; ++dx)
                k1 += (int)cs2s[(r + dy) * 34 + (c + dx)];
        const int rc = (gy == 0) ? 0 : ((gy == 191) ? 2 : 1);
        const int cls = rc * 3 + cc;
        const float t2 = C2 * (float)k1;
#pragma unroll
        for (int reg = 0; reg < 16; ++reg) {
            const int co = (reg & 3) + 8 * (reg >> 2) + 4 * ch;
            const float y = fmaf(C1, (float)acc[m][reg], t2 + tlds[cls * 32 + co]);
            out[(((size_t)n * 32 + co) * 192 + gy) * 192 + gx] = y;
        }
    }
}

extern "C" void kernel_launch(void* const* d_in, const int* in_sizes, int n_in,
                              void* d_out, int out_size, void* d_ws, size_t ws_size,
                              hipStream_t stream) {
    const float* x      = (const float*)d_in[0];
    const float* weight = (const float*)d_in[1];
    const float* bias   = (const float*)d_in[2];
    const int*   bits   = (const int*)d_in[3];
    float* out = (float*)d_out;

    float* ws       = (float*)d_ws;
    float* partials = ws;                           // 2304 floats
    float* gstats   = ws + 2304;                    // 8
    float* coefs    = ws + 2312;                    // 8
    float* tbl      = ws + 2320;                    // 864
    int*   colJ     = (int*)(ws + 3184);            // 864 ints
    unsigned int* wq8 = (unsigned int*)(ws + 4048); // 6912 u32 (byte off 16192, 16-aligned)

    kA_partial_minmax<<<32 * 36, 256, 0, stream>>>(x, partials);
    kW_weights<<<27, 256, 0, stream>>>(weight, wq8, colJ);
    kB2_stats_tbl<<<1, 256, 0, stream>>>(weight, bias, bits, partials, colJ, gstats, coefs, tbl);

    dim3 grid(6, 12, 32);
    kC_conv<<<grid, 256, 0, stream>>>(x, bits, gstats, coefs, tbl, wq8, out);
}

// Round 8
// 120.560 us; speedup vs baseline: 3.8234x; 1.2161x over previous
//
#include <hip/hip_runtime.h>

#define EPSQ 1e-8f

typedef int v4i  __attribute__((ext_vector_type(4)));
typedef int v16i __attribute__((ext_vector_type(16)));

// x: (32, 32, 192, 192) f32; weight: (32, 32, 3, 3) f32; bias: (32,) f32; bits: (32,) i32
//
// Integer-exact decomposition (per batch n with group g, σ=2^(b-1)):
//   x_q = mn + s·k,  w_q = wm + t·j,  kc = k−σ, jc = j−σ  (i8, centered)
//   y[p,co] = s·t·KJ[p,co] + s·(wm+σt)·K1[p] + Tbl[class(p)][co]
//   KJ = Σ_{taps,ci} kc·jc  (i8 MFMA, exact i32; pad kc=0)
//   K1 = Σ_{taps,ci} kc     (box sum of per-pixel ci-sums; pad 0)
// k and j use the same IEEE f32 div + rintf as the reference → identical quant decisions.
//
// r8: quantization hoisted into kQ (codes[n][y][x][ci] i8 in d_ws, 37.7 MB);
// kC stages 32B/px of codes (no divs, no f32 gathers). Fallback to the r7
// fused path when ws_size is too small for the code array.

__device__ __forceinline__ int bytesum4(int v) {
#if __has_builtin(__builtin_amdgcn_sdot4)
    return __builtin_amdgcn_sdot4(v, 0x01010101, 0, false);
#else
    return (int)(char)(v) + (int)(char)(v >> 8) + (int)(char)(v >> 16) + (int)(char)(v >> 24);
#endif
}

// ---------------- Kernel AW: x min/max partials (blocks 0..1151) + weight codes (1152..1178) ----------------
// partials[(batch*36+blk)*2 + {0,1}]
// wq8[((g*9+tap)*64+lane)*4 + a4]; byte i: co=lane&31, ci=(lane>>5)*16+a4*4+i
// colJ[g*288 + tap*32 + co] = Σ_ci jc ; wstats[0,1] = wmin, wmax
__global__ __launch_bounds__(256) void kAW(
    const float* __restrict__ x, const float* __restrict__ w,
    float* __restrict__ partials, unsigned int* __restrict__ wq8,
    int* __restrict__ colJ, float* __restrict__ wstats)
{
    __shared__ float smn[256], smx[256];
    __shared__ int   jred[256];
    __shared__ float s_wmn, s_wmx;
    const int tid = threadIdx.x;

    if (blockIdx.x < 1152) {
        const int batch = blockIdx.x / 36;
        const int blk   = blockIdx.x % 36;
        const float* xb = x + (size_t)batch * 1179648 + (size_t)blk * 32768;
        float mn = INFINITY, mx = -INFINITY;
#pragma unroll
        for (int i = 0; i < 32; ++i) {
            const float4 v = reinterpret_cast<const float4*>(xb)[i * 256 + tid];
            mn = fminf(mn, fminf(fminf(v.x, v.y), fminf(v.z, v.w)));
            mx = fmaxf(mx, fmaxf(fmaxf(v.x, v.y), fmaxf(v.z, v.w)));
        }
        smn[tid] = mn; smx[tid] = mx;
        __syncthreads();
        for (int s = 128; s > 0; s >>= 1) {
            if (tid < s) {
                smn[tid] = fminf(smn[tid], smn[tid + s]);
                smx[tid] = fmaxf(smx[tid], smx[tid + s]);
            }
            __syncthreads();
        }
        if (tid == 0) {
            partials[blockIdx.x * 2 + 0] = smn[0];
            partials[blockIdx.x * 2 + 1] = smx[0];
        }
        return;
    }

    // ---- weight blocks: one per (g, tap) ----
    const int wb  = blockIdx.x - 1152;
    const int g   = wb / 9;
    const int tap = wb % 9;

    float wmn = INFINITY, wmx = -INFINITY;
    for (int i = tid; i < 9216; i += 256) {
        const float v = w[i];
        wmn = fminf(wmn, v); wmx = fmaxf(wmx, v);
    }
    smn[tid] = wmn; smx[tid] = wmx; __syncthreads();
    for (int s = 128; s > 0; s >>= 1) {
        if (tid < s) {
            smn[tid] = fminf(smn[tid], smn[tid + s]);
            smx[tid] = fmaxf(smx[tid], smx[tid + s]);
        }
        __syncthreads();
    }
    if (tid == 0) { s_wmn = smn[0]; s_wmx = smx[0]; }
    __syncthreads();
    if (wb == 0 && tid == 0) { wstats[0] = s_wmn; wstats[1] = s_wmx; }

    const float wmv = s_wmn, wxv = s_wmx;
    const int bval = 2 << g;
    const float denom = (float)((1 << bval) - 1);
    const float t = fmaxf((wxv - wmv) / denom, EPSQ);
    const int sig = 1 << (bval - 1);

    const int co = tid & 31;
    const int q  = tid >> 5;          // ci-quad 0..7
    unsigned int packed = 0;
    int jsum = 0;
#pragma unroll
    for (int b = 0; b < 4; ++b) {
        const int ci = q * 4 + b;
        int jc = (int)rintf((w[co * 288 + ci * 9 + tap] - wmv) / t) - sig;  // IEEE div, as ref
        jc = jc < -128 ? -128 : (jc > 127 ? 127 : jc);                      // no-op for b<=8
        jsum += jc;
        packed |= ((unsigned int)(unsigned char)(char)jc) << (8 * b);
    }
    const int lane_ = (q >> 2) * 32 + co;
    const int a4    = q & 3;
    wq8[((size_t)(g * 9 + tap) * 64 + lane_) * 4 + a4] = packed;

    jred[tid] = jsum; __syncthreads();
    if (tid < 128) jred[tid] += jred[tid + 128];
    __syncthreads();
    if (tid < 64) jred[tid] += jred[tid + 64];
    __syncthreads();
    if (tid < 32) colJ[g * 288 + tap * 32 + tid] = jred[tid] + jred[tid + 32];
}

// ---------------- Kernel B2: group stats + coefs + Tbl (1 block) ----------------
__global__ __launch_bounds__(256) void kB2_stats_tbl(
    const float* __restrict__ bias, const int* __restrict__ bits,
    const float* __restrict__ partials, const int* __restrict__ colJ,
    const float* __restrict__ wstats,
    float* __restrict__ gstats, float* __restrict__ coefs, float* __restrict__ tbl)
{
    __shared__ float bmn[32], bmx[32];
    __shared__ float s_gmn[3], s_gs[3];
    const int tid = threadIdx.x;
    const float wmv = wstats[0], wxv = wstats[1];

    if (tid < 32) {
        float mn = INFINITY, mx = -INFINITY;
        for (int i = 0; i < 36; ++i) {
            mn = fminf(mn, partials[(tid * 36 + i) * 2 + 0]);
            mx = fmaxf(mx, partials[(tid * 36 + i) * 2 + 1]);
        }
        bmn[tid] = mn; bmx[tid] = mx;
    }
    __syncthreads();

    if (tid < 3) {
        const int bval = 2 << tid;
        const float denom = (float)((1 << bval) - 1);
        float mn = INFINITY, mx = -INFINITY; bool has = false;
        for (int nb = 0; nb < 32; ++nb) {
            if (bits[nb] == bval) { has = true; mn = fminf(mn, bmn[nb]); mx = fmaxf(mx, bmx[nb]); }
        }
        if (!has) { mn = 0.f; mx = 0.f; }
        const float scale = fmaxf((mx - mn) / denom, EPSQ);
        gstats[tid * 2 + 0] = mn;
        gstats[tid * 2 + 1] = scale;
        s_gmn[tid] = mn; s_gs[tid] = scale;

        const float t = fmaxf((wxv - wmv) / denom, EPSQ);
        const int sig = 1 << (bval - 1);
        const double B_ = (double)wmv + (double)sig * (double)t;
        coefs[tid * 2 + 0] = (float)((double)scale * (double)t);
        coefs[tid * 2 + 1] = (float)((double)scale * B_);
    }
    __syncthreads();

    for (int idx = tid; idx < 864; idx += 256) {
        const int g   = idx / 288;
        const int rem = idx % 288;
        const int cls = rem / 32;
        const int co  = rem % 32;
        const int bval = 2 << g;
        const float denom = (float)((1 << bval) - 1);
        const float t = fmaxf((wxv - wmv) / denom, EPSQ);
        const int sig = 1 << (bval - 1);
        const double A_ = (double)s_gmn[g] + (double)sig * (double)s_gs[g];
        const double B_ = (double)wmv + (double)sig * (double)t;
        const int rc = cls / 3, cc = cls % 3;
        double js = 0.0, ij = 0.0; int ninv = 0;
        for (int tap = 0; tap < 9; ++tap) {
            const int dy = tap / 3, dx = tap % 3;
            const int cj = colJ[g * 288 + tap * 32 + co];
            js += (double)cj;
            const bool inv = (rc == 0 && dy == 0) || (rc == 2 && dy == 2) ||
                             (cc == 0 && dx == 0) || (cc == 2 && dx == 2);
            if (inv) { ++ninv; ij += (double)cj; }
        }
        const double v = (double)t * A_ * js + 288.0 * A_ * B_ + (double)bias[co]
                       - A_ * (32.0 * B_ * (double)ninv + (double)t * ij);
        tbl[idx] = (float)v;
    }
}

// ---------------- Kernel Q: quantize all of x to channel-last i8 codes ----------------
// codes[n][py*192+px][ci] i8, 32 B per pixel. grid = 32*36 blocks; thread: 4 px x 32 ci.
// Reads coalesced float4 per ci-plane; writes 128 B contiguous per thread.
__global__ __launch_bounds__(256) void kQ_quant(
    const float* __restrict__ x, const int* __restrict__ bits,
    const float* __restrict__ gstats, unsigned int* __restrict__ codes)
{
    const int n     = blockIdx.x / 36;
    const int chunk = blockIdx.x % 36;
    const int bval = bits[n];
    const int g = (bval == 2) ? 0 : (bval == 4 ? 1 : 2);
    const int sig = 1 << (bval - 1);
    const float mn = gstats[g * 2 + 0];
    const float s  = gstats[g * 2 + 1];

    const int px0 = chunk * 1024 + threadIdx.x * 4;     // 4 consecutive px
    const float* xn = x + (size_t)n * 1179648;

    unsigned int creg[32];                               // [p][ci>>2], all static
#pragma unroll
    for (int i = 0; i < 32; ++i) creg[i] = 0;

#pragma unroll
    for (int ci = 0; ci < 32; ++ci) {
        const float4 v = *(const float4*)(xn + (size_t)ci * 36864 + px0);
        const float vv[4] = {v.x, v.y, v.z, v.w};
#pragma unroll
        for (int p = 0; p < 4; ++p) {
            // IEEE f32 div + rintf: identical quant decisions to reference
            int kq = (int)rintf((vv[p] - mn) / s) - sig;
            kq = kq < -128 ? -128 : (kq > 127 ? 127 : kq);   // no-op for b<=8
            creg[p * 8 + (ci >> 2)] |= ((unsigned int)(unsigned char)(char)kq) << (8 * (ci & 3));
        }
    }

    unsigned int* cp = codes + ((size_t)n * 36864 + (size_t)px0) * 8;
#pragma unroll
    for (int p = 0; p < 4; ++p) {
        *(v4i*)(cp + p * 8 + 0) = (v4i){(int)creg[p*8+0], (int)creg[p*8+1], (int)creg[p*8+2], (int)creg[p*8+3]};
        *(v4i*)(cp + p * 8 + 4) = (v4i){(int)creg[p*8+4], (int)creg[p*8+5], (int)creg[p*8+6], (int)creg[p*8+7]};
    }
}

// ---------------- Kernel C (codes path): i8-MFMA conv ----------------
// grid = (6, 12, 32); block 256 (4 waves). Tile 16 rows x 32 cols, all 32 co.
// Staging: 32 B of codes per px (2 loads + 2 ds_write_b128 + sdot4 sums). No divs.
__global__ __launch_bounds__(256, 4) void kC_codes(
    const unsigned int* __restrict__ codes, const int* __restrict__ bits,
    const float* __restrict__ coefs, const float* __restrict__ tbl,
    const unsigned int* __restrict__ wq8, float* __restrict__ out)
{
    __shared__ v4i   xkv[18 * 34 * 3];   // 29376 B : centered i8 codes [px][48B pitch]
    __shared__ short cs2s[18 * 34];      // per-pixel Σ_ci kc
    __shared__ float tlds[288];

    const int n  = blockIdx.z;
    const int oy = blockIdx.y * 16;
    const int ox = blockIdx.x * 32;
    const int tid  = threadIdx.x;
    const int lane = tid & 63;
    const int wv   = tid >> 6;

    const int bval = bits[n];
    const int g = (bval == 2) ? 0 : (bval == 4 ? 1 : 2);
    const float C1 = coefs[g * 2 + 0];
    const float C2 = coefs[g * 2 + 1];

    const v4i* wA = (const v4i*)(wq8 + (size_t)g * 2304);
    v4i wfr[9];
#pragma unroll
    for (int t = 0; t < 9; ++t) wfr[t] = wA[t * 64 + lane];

    for (int i = tid; i < 288; i += 256) tlds[i] = tbl[g * 288 + i];

    // ---- stage codes (pad -> 0) ----
    const unsigned int* cb = codes + (size_t)n * 36864 * 8;
    char* xk = (char*)xkv;
    for (int px = tid; px < 612; px += 256) {
        const int r = px / 34;
        const int c = px - r * 34;
        const int gy = oy + r - 1, gx = ox + c - 1;
        v4i pk0 = (v4i){0,0,0,0}, pk1 = (v4i){0,0,0,0};
        int ksum = 0;
        if (((unsigned)gy < 192u) && ((unsigned)gx < 192u)) {
            const unsigned int* p = cb + ((size_t)gy * 192 + gx) * 8;
            pk0 = *(const v4i*)(p + 0);
            pk1 = *(const v4i*)(p + 4);
            ksum = bytesum4(pk0.x) + bytesum4(pk0.y) + bytesum4(pk0.z) + bytesum4(pk0.w)
                 + bytesum4(pk1.x) + bytesum4(pk1.y) + bytesum4(pk1.z) + bytesum4(pk1.w);
        }
        *(v4i*)(xk + px * 48 +  0) = pk0;
        *(v4i*)(xk + px * 48 + 16) = pk1;
        cs2s[px] = (short)ksum;
    }
    __syncthreads();

    // ---- MFMA conv + epilogue (one 4-row quad per wave) ----
    const int c  = lane & 31;
    const int ch = lane >> 5;
    const int gx = ox + c;
    const int cc = (gx == 0) ? 0 : ((gx == 191) ? 2 : 1);
    const int r0 = wv * 4;

    v16i acc[4] = {};
#pragma unroll
    for (int dyr = 0; dyr < 6; ++dyr) {
        const int xrow = r0 + dyr;
        const v4i bf0 = xkv[(xrow * 34 + c + 0) * 3 + ch];
        const v4i bf1 = xkv[(xrow * 34 + c + 1) * 3 + ch];
        const v4i bf2 = xkv[(xrow * 34 + c + 2) * 3 + ch];
#pragma unroll
        for (int m = 0; m < 4; ++m) {
            const int dy = dyr - m;
            if (dy >= 0 && dy < 3) {
                acc[m] = __builtin_amdgcn_mfma_i32_32x32x32_i8(wfr[dy * 3 + 0], bf0, acc[m], 0, 0, 0);
                acc[m] = __builtin_amdgcn_mfma_i32_32x32x32_i8(wfr[dy * 3 + 1], bf1, acc[m], 0, 0, 0);
                acc[m] = __builtin_amdgcn_mfma_i32_32x32x32_i8(wfr[dy * 3 + 2], bf2, acc[m], 0, 0, 0);
            }
        }
    }

#pragma unroll
    for (int m = 0; m < 4; ++m) {
        const int r  = r0 + m;
        const int gy = oy + r;
        int k1 = 0;
#pragma unroll
        for (int dy = 0; dy < 3; ++dy)
#pragma unroll
            for (int dx = 0; dx < 3; ++dx)
                k1 += (int)cs2s[(r + dy) * 34 + (c + dx)];
        const int rc = (gy == 0) ? 0 : ((gy == 191) ? 2 : 1);
        const int cls = rc * 3 + cc;
        const float t2 = C2 * (float)k1;
#pragma unroll
        for (int reg = 0; reg < 16; ++reg) {
            const int co = (reg & 3) + 8 * (reg >> 2) + 4 * ch;
            const float y = fmaf(C1, (float)acc[m][reg], t2 + tlds[cls * 32 + co]);
            out[(((size_t)n * 32 + co) * 192 + gy) * 192 + gx] = y;
        }
    }
}

// ---------------- Kernel C (fallback, r7 fused path) ----------------
__global__ __launch_bounds__(256, 4) void kC_fused(
    const float* __restrict__ x, const int* __restrict__ bits,
    const float* __restrict__ gstats, const float* __restrict__ coefs,
    const float* __restrict__ tbl, const unsigned int* __restrict__ wq8,
    float* __restrict__ out)
{
    __shared__ v4i   xkv[18 * 34 * 3];
    __shared__ short cs2s[18 * 34];
    __shared__ float tlds[288];

    const int n  = blockIdx.z;
    const int oy = blockIdx.y * 16;
    const int ox = blockIdx.x * 32;
    const int tid  = threadIdx.x;
    const int lane = tid & 63;
    const int wv   = tid >> 6;

    const int bval = bits[n];
    const int g = (bval == 2) ? 0 : (bval == 4 ? 1 : 2);
    const int sig = 1 << (bval - 1);
    const float mn = gstats[g * 2 + 0];
    const float s  = gstats[g * 2 + 1];
    const float C1 = coefs[g * 2 + 0];
    const float C2 = coefs[g * 2 + 1];

    const v4i* wA = (const v4i*)(wq8 + (size_t)g * 2304);
    v4i wfr[9];
#pragma unroll
    for (int t = 0; t < 9; ++t) wfr[t] = wA[t * 64 + lane];

    for (int i = tid; i < 288; i += 256) tlds[i] = tbl[g * 288 + i];

    const float* xn = x + (size_t)n * 1179648;
    char* xk = (char*)xkv;
    for (int px = tid; px < 612; px += 256) {
        const int r = px / 34;
        const int c = px - r * 34;
        const int gy = oy + r - 1, gx = ox + c - 1;
        const bool valid = ((unsigned)gy < 192u) && ((unsigned)gx < 192u);
        const float* xp = xn + (size_t)(valid ? gy : 0) * 192 + (valid ? gx : 0);
        int ksum = 0;
        v4i pk0, pk1;
#pragma unroll
        for (int h = 0; h < 2; ++h) {
            float v[16];
#pragma unroll
            for (int i = 0; i < 16; ++i) v[i] = xp[(size_t)(h * 16 + i) * 36864];
            int w4[4];
#pragma unroll
            for (int q4 = 0; q4 < 4; ++q4) {
                unsigned int pw = 0;
#pragma unroll
                for (int b = 0; b < 4; ++b) {
                    int kq = (int)rintf((v[q4 * 4 + b] - mn) / s) - sig;
                    kq = kq < -128 ? -128 : (kq > 127 ? 127 : kq);
                    ksum += kq;
                    pw |= ((unsigned int)(unsigned char)(char)kq) << (8 * b);
                }
                w4[q4] = (int)pw;
            }
            if (h == 0) pk0 = (v4i){w4[0], w4[1], w4[2], w4[3]};
            else        pk1 = (v4i){w4[0], w4[1], w4[2], w4[3]};
        }
        if (!valid) { pk0 = (v4i){0,0,0,0}; pk1 = (v4i){0,0,0,0}; ksum = 0; }
        *(v4i*)(xk + px * 48 +  0) = pk0;
        *(v4i*)(xk + px * 48 + 16) = pk1;
        cs2s[px] = (short)ksum;
    }
    __syncthreads();

    const int c  = lane & 31;
    const int ch = lane >> 5;
    const int gx = ox + c;
    const int cc = (gx == 0) ? 0 : ((gx == 191) ? 2 : 1);
    const int r0 = wv * 4;

    v16i acc[4] = {};
#pragma unroll
    for (int dyr = 0; dyr < 6; ++dyr) {
        const int xrow = r0 + dyr;
        const v4i bf0 = xkv[(xrow * 34 + c + 0) * 3 + ch];
        const v4i bf1 = xkv[(xrow * 34 + c + 1) * 3 + ch];
        const v4i bf2 = xkv[(xrow * 34 + c + 2) * 3 + ch];
#pragma unroll
        for (int m = 0; m < 4; ++m) {
            const int dy = dyr - m;
            if (dy >= 0 && dy < 3) {
                acc[m] = __builtin_amdgcn_mfma_i32_32x32x32_i8(wfr[dy * 3 + 0], bf0, acc[m], 0, 0, 0);
                acc[m] = __builtin_amdgcn_mfma_i32_32x32x32_i8(wfr[dy * 3 + 1], bf1, acc[m], 0, 0, 0);
                acc[m] = __builtin_amdgcn_mfma_i32_32x32x32_i8(wfr[dy * 3 + 2], bf2, acc[m], 0, 0, 0);
            }
        }
    }

#pragma unroll
    for (int m = 0; m < 4; ++m) {
        const int r  = r0 + m;
        const int gy = oy + r;
        int k1 = 0;
#pragma unroll
        for (int dy = 0; dy < 3; ++dy)
#pragma unroll
            for (int dx = 0; dx < 3; ++dx)
                k1 += (int)cs2s[(r + dy) * 34 + (c + dx)];
        const int rc = (gy == 0) ? 0 : ((gy == 191) ? 2 : 1);
        const int cls = rc * 3 + cc;
        const float t2 = C2 * (float)k1;
#pragma unroll
        for (int reg = 0; reg < 16; ++reg) {
            const int co = (reg & 3) + 8 * (reg >> 2) + 4 * ch;
            const float y = fmaf(C1, (float)acc[m][reg], t2 + tlds[cls * 32 + co]);
            out[(((size_t)n * 32 + co) * 192 + gy) * 192 + gx] = y;
        }
    }
}

extern "C" void kernel_launch(void* const* d_in, const int* in_sizes, int n_in,
                              void* d_out, int out_size, void* d_ws, size_t ws_size,
                              hipStream_t stream) {
    const float* x      = (const float*)d_in[0];
    const float* weight = (const float*)d_in[1];
    const float* bias   = (const float*)d_in[2];
    const int*   bits   = (const int*)d_in[3];
    float* out = (float*)d_out;

    float* ws       = (float*)d_ws;
    float* partials = ws;                            // 2304 floats
    float* gstats   = ws + 2304;                     // 8
    float* coefs    = ws + 2312;                     // 8
    float* tbl      = ws + 2320;                     // 864
    int*   colJ     = (int*)(ws + 3184);             // 864 ints
    unsigned int* wq8 = (unsigned int*)(ws + 4048);  // 6912 u32 -> ends float-idx 10960
    float* wstats   = ws + 10960;                    // 2 floats
    // codes: 64B-aligned offset 43904 bytes, 37748736 bytes
    const size_t codes_off   = 43904;
    const size_t codes_bytes = 37748736ull;
    unsigned int* codes = (unsigned int*)((char*)d_ws + codes_off);
    const bool big_ws = ws_size >= codes_off + codes_bytes;

    kAW<<<1179, 256, 0, stream>>>(x, weight, partials, wq8, colJ, wstats);
    kB2_stats_tbl<<<1, 256, 0, stream>>>(bias, bits, partials, colJ, wstats, gstats, coefs, tbl);

    dim3 grid(6, 12, 32);
    if (big_ws) {
        kQ_quant<<<32 * 36, 256, 0, stream>>>(x, bits, gstats, codes);
        kC_codes<<<grid, 256, 0, stream>>>(codes, bits, coefs, tbl, wq8, out);
    } else {
        kC_fused<<<grid, 256, 0, stream>>>(x, bits, gstats, coefs, tbl, wq8, out);
    }
}

// Round 9
// 118.647 us; speedup vs baseline: 3.8850x; 1.0161x over previous
//
#include <hip/hip_runtime.h>

#define EPSQ 1e-8f

typedef int v4i  __attribute__((ext_vector_type(4)));
typedef int v16i __attribute__((ext_vector_type(16)));

// x: (32, 32, 192, 192) f32; weight: (32, 32, 3, 3) f32; bias: (32,) f32; bits: (32,) i32
//
// Integer-exact decomposition (per batch n with group g, σ=2^(b-1)):
//   x_q = mn + s·k,  w_q = wm + t·j,  kc = k−σ, jc = j−σ  (i8, centered)
//   y[p,co] = s·t·KJ[p,co] + s·(wm+σt)·K1[p] + Tbl[class(p)][co]
//   KJ = Σ_{taps,ci} kc·jc  (i8 MFMA, exact i32; pad kc=0)
//   K1 = Σ_{taps,ci} kc     (box sum of per-pixel ci-sums; pad 0)
// k and j use the same IEEE f32 div + rintf as the reference → identical quant decisions.
//
// r9: 3-launch chain kAW -> kQ -> kC. kQ computes group stats inline from
// partials; kC computes coefs+Tbl inline (old kB2 folded in). Codes path
// byte-identical to r8.

__device__ __forceinline__ int bytesum4(int v) {
#if __has_builtin(__builtin_amdgcn_sdot4)
    return __builtin_amdgcn_sdot4(v, 0x01010101, 0, false);
#else
    return (int)(char)(v) + (int)(char)(v >> 8) + (int)(char)(v >> 16) + (int)(char)(v >> 24);
#endif
}

// ---------------- Kernel AW: x min/max partials (blocks 0..1151) + weight codes (1152..1178) ----------------
__global__ __launch_bounds__(256) void kAW(
    const float* __restrict__ x, const float* __restrict__ w,
    float* __restrict__ partials, unsigned int* __restrict__ wq8,
    int* __restrict__ colJ, float* __restrict__ wstats)
{
    __shared__ float smn[256], smx[256];
    __shared__ int   jred[256];
    __shared__ float s_wmn, s_wmx;
    const int tid = threadIdx.x;

    if (blockIdx.x < 1152) {
        const int batch = blockIdx.x / 36;
        const int blk   = blockIdx.x % 36;
        const float* xb = x + (size_t)batch * 1179648 + (size_t)blk * 32768;
        float mn = INFINITY, mx = -INFINITY;
#pragma unroll
        for (int i = 0; i < 32; ++i) {
            const float4 v = reinterpret_cast<const float4*>(xb)[i * 256 + tid];
            mn = fminf(mn, fminf(fminf(v.x, v.y), fminf(v.z, v.w)));
            mx = fmaxf(mx, fmaxf(fmaxf(v.x, v.y), fmaxf(v.z, v.w)));
        }
        smn[tid] = mn; smx[tid] = mx;
        __syncthreads();
        for (int s = 128; s > 0; s >>= 1) {
            if (tid < s) {
                smn[tid] = fminf(smn[tid], smn[tid + s]);
                smx[tid] = fmaxf(smx[tid], smx[tid + s]);
            }
            __syncthreads();
        }
        if (tid == 0) {
            partials[blockIdx.x * 2 + 0] = smn[0];
            partials[blockIdx.x * 2 + 1] = smx[0];
        }
        return;
    }

    const int wb  = blockIdx.x - 1152;
    const int g   = wb / 9;
    const int tap = wb % 9;

    float wmn = INFINITY, wmx = -INFINITY;
    for (int i = tid; i < 9216; i += 256) {
        const float v = w[i];
        wmn = fminf(wmn, v); wmx = fmaxf(wmx, v);
    }
    smn[tid] = wmn; smx[tid] = wmx; __syncthreads();
    for (int s = 128; s > 0; s >>= 1) {
        if (tid < s) {
            smn[tid] = fminf(smn[tid], smn[tid + s]);
            smx[tid] = fmaxf(smx[tid], smx[tid + s]);
        }
        __syncthreads();
    }
    if (tid == 0) { s_wmn = smn[0]; s_wmx = smx[0]; }
    __syncthreads();
    if (wb == 0 && tid == 0) { wstats[0] = s_wmn; wstats[1] = s_wmx; }

    const float wmv = s_wmn, wxv = s_wmx;
    const int bval = 2 << g;
    const float denom = (float)((1 << bval) - 1);
    const float t = fmaxf((wxv - wmv) / denom, EPSQ);
    const int sig = 1 << (bval - 1);

    const int co = tid & 31;
    const int q  = tid >> 5;
    unsigned int packed = 0;
    int jsum = 0;
#pragma unroll
    for (int b = 0; b < 4; ++b) {
        const int ci = q * 4 + b;
        int jc = (int)rintf((w[co * 288 + ci * 9 + tap] - wmv) / t) - sig;  // IEEE div, as ref
        jc = jc < -128 ? -128 : (jc > 127 ? 127 : jc);
        jsum += jc;
        packed |= ((unsigned int)(unsigned char)(char)jc) << (8 * b);
    }
    const int lane_ = (q >> 2) * 32 + co;
    const int a4    = q & 3;
    wq8[((size_t)(g * 9 + tap) * 64 + lane_) * 4 + a4] = packed;

    jred[tid] = jsum; __syncthreads();
    if (tid < 128) jred[tid] += jred[tid + 128];
    __syncthreads();
    if (tid < 64) jred[tid] += jred[tid + 64];
    __syncthreads();
    if (tid < 32) colJ[g * 288 + tap * 32 + tid] = jred[tid] + jred[tid + 32];
}

// ---------------- Kernel Q: quantize all of x to channel-last i8 codes (stats inline) ----------------
__global__ __launch_bounds__(256) void kQ_quant(
    const float* __restrict__ x, const int* __restrict__ bits,
    const float* __restrict__ partials, unsigned int* __restrict__ codes)
{
    __shared__ float bmn[32], bmx[32];
    __shared__ float s_mn, s_sc;

    const int n     = blockIdx.x / 36;
    const int chunk = blockIdx.x % 36;
    const int tid   = threadIdx.x;
    const int bval  = bits[n];
    const int sig   = 1 << (bval - 1);

    if (tid < 32) {
        float mn = INFINITY, mx = -INFINITY;
        for (int i = 0; i < 36; ++i) {
            mn = fminf(mn, partials[(tid * 36 + i) * 2 + 0]);
            mx = fmaxf(mx, partials[(tid * 36 + i) * 2 + 1]);
        }
        bmn[tid] = mn; bmx[tid] = mx;
    }
    __syncthreads();
    if (tid == 0) {
        float mn = INFINITY, mx = -INFINITY;
        for (int nb = 0; nb < 32; ++nb)
            if (bits[nb] == bval) { mn = fminf(mn, bmn[nb]); mx = fmaxf(mx, bmx[nb]); }
        const float denom = (float)((1 << bval) - 1);
        s_mn = mn;
        s_sc = fmaxf((mx - mn) / denom, EPSQ);
    }
    __syncthreads();
    const float mn = s_mn, s = s_sc;

    const int px0 = chunk * 1024 + tid * 4;
    const float* xn = x + (size_t)n * 1179648;

    unsigned int creg[32];
#pragma unroll
    for (int i = 0; i < 32; ++i) creg[i] = 0;

#pragma unroll
    for (int ci = 0; ci < 32; ++ci) {
        const float4 v = *(const float4*)(xn + (size_t)ci * 36864 + px0);
        const float vv[4] = {v.x, v.y, v.z, v.w};
#pragma unroll
        for (int p = 0; p < 4; ++p) {
            // IEEE f32 div + rintf: identical quant decisions to reference
            int kq = (int)rintf((vv[p] - mn) / s) - sig;
            kq = kq < -128 ? -128 : (kq > 127 ? 127 : kq);
            creg[p * 8 + (ci >> 2)] |= ((unsigned int)(unsigned char)(char)kq) << (8 * (ci & 3));
        }
    }

    unsigned int* cp = codes + ((size_t)n * 36864 + (size_t)px0) * 8;
#pragma unroll
    for (int p = 0; p < 4; ++p) {
        *(v4i*)(cp + p * 8 + 0) = (v4i){(int)creg[p*8+0], (int)creg[p*8+1], (int)creg[p*8+2], (int)creg[p*8+3]};
        *(v4i*)(cp + p * 8 + 4) = (v4i){(int)creg[p*8+4], (int)creg[p*8+5], (int)creg[p*8+6], (int)creg[p*8+7]};
    }
}

// ---------------- Kernel C: i8-MFMA conv, coefs+Tbl inline ----------------
// grid = (6, 12, 32); block 256 (4 waves). Tile 16 rows x 32 cols, all 32 co.
__global__ __launch_bounds__(256, 4) void kC_codes(
    const unsigned int* __restrict__ codes, const int* __restrict__ bits,
    const float* __restrict__ partials, const int* __restrict__ colJ,
    const float* __restrict__ wstats, const float* __restrict__ bias,
    const unsigned int* __restrict__ wq8, float* __restrict__ out)
{
    __shared__ v4i   xkv[18 * 34 * 3];   // centered i8 codes [px][48B pitch]
    __shared__ short cs2s[18 * 34];
    __shared__ float tlds[288];
    __shared__ float bmn[32], bmx[32];
    __shared__ float s_stats[4];         // gmn, gs, C1, C2

    const int n  = blockIdx.z;
    const int oy = blockIdx.y * 16;
    const int ox = blockIdx.x * 32;
    const int tid  = threadIdx.x;
    const int lane = tid & 63;
    const int wv   = tid >> 6;

    const int bval = bits[n];
    const int g = (bval == 2) ? 0 : (bval == 4 ? 1 : 2);
    const int sig = 1 << (bval - 1);
    const float denom = (float)((1 << bval) - 1);

    // ---- group stats (identical ops to r8's kB2) ----
    if (tid < 32) {
        float mn = INFINITY, mx = -INFINITY;
        for (int i = 0; i < 36; ++i) {
            mn = fminf(mn, partials[(tid * 36 + i) * 2 + 0]);
            mx = fmaxf(mx, partials[(tid * 36 + i) * 2 + 1]);
        }
        bmn[tid] = mn; bmx[tid] = mx;
    }
    __syncthreads();
    if (tid == 0) {
        float mn = INFINITY, mx = -INFINITY;
        for (int nb = 0; nb < 32; ++nb)
            if (bits[nb] == bval) { mn = fminf(mn, bmn[nb]); mx = fmaxf(mx, bmx[nb]); }
        const float scale = fmaxf((mx - mn) / denom, EPSQ);
        const float wmv = wstats[0], wxv = wstats[1];
        const float t = fmaxf((wxv - wmv) / denom, EPSQ);
        const double B_ = (double)wmv + (double)sig * (double)t;
        s_stats[0] = mn;
        s_stats[1] = scale;
        s_stats[2] = (float)((double)scale * (double)t);   // C1
        s_stats[3] = (float)((double)scale * B_);          // C2
    }
    __syncthreads();
    const float C1 = s_stats[2];
    const float C2 = s_stats[3];

    // ---- Tbl inline (exact kB2 math, f64, same tap order) ----
    {
        const float wmv = wstats[0], wxv = wstats[1];
        const float t = fmaxf((wxv - wmv) / denom, EPSQ);
        const double A_ = (double)s_stats[0] + (double)sig * (double)s_stats[1];
        const double B_ = (double)wmv + (double)sig * (double)t;
        for (int idx = tid; idx < 288; idx += 256) {
            const int cls = idx / 32;
            const int co  = idx % 32;
            const int rc = cls / 3, cc = cls % 3;
            double js = 0.0, ij = 0.0; int ninv = 0;
            for (int tap = 0; tap < 9; ++tap) {
                const int dy = tap / 3, dx = tap % 3;
                const int cj = colJ[g * 288 + tap * 32 + co];
                js += (double)cj;
                const bool inv = (rc == 0 && dy == 0) || (rc == 2 && dy == 2) ||
                                 (cc == 0 && dx == 0) || (cc == 2 && dx == 2);
                if (inv) { ++ninv; ij += (double)cj; }
            }
            const double v = (double)t * A_ * js + 288.0 * A_ * B_ + (double)bias[co]
                           - A_ * (32.0 * B_ * (double)ninv + (double)t * ij);
            tlds[idx] = (float)v;
        }
    }

    // ---- weights -> registers (9 A-frags) ----
    const v4i* wA = (const v4i*)(wq8 + (size_t)g * 2304);
    v4i wfr[9];
#pragma unroll
    for (int t = 0; t < 9; ++t) wfr[t] = wA[t * 64 + lane];

    // ---- stage codes (pad -> 0) ----
    const unsigned int* cb = codes + (size_t)n * 36864 * 8;
    char* xk = (char*)xkv;
    for (int px = tid; px < 612; px += 256) {
        const int r = px / 34;
        const int c = px - r * 34;
        const int gy = oy + r - 1, gx = ox + c - 1;
        v4i pk0 = (v4i){0,0,0,0}, pk1 = (v4i){0,0,0,0};
        int ksum = 0;
        if (((unsigned)gy < 192u) && ((unsigned)gx < 192u)) {
            const unsigned int* p = cb + ((size_t)gy * 192 + gx) * 8;
            pk0 = *(const v4i*)(p + 0);
            pk1 = *(const v4i*)(p + 4);
            ksum = bytesum4(pk0.x) + bytesum4(pk0.y) + bytesum4(pk0.z) + bytesum4(pk0.w)
                 + bytesum4(pk1.x) + bytesum4(pk1.y) + bytesum4(pk1.z) + bytesum4(pk1.w);
        }
        *(v4i*)(xk + px * 48 +  0) = pk0;
        *(v4i*)(xk + px * 48 + 16) = pk1;
        cs2s[px] = (short)ksum;
    }
    __syncthreads();

    // ---- MFMA conv + epilogue (one 4-row quad per wave) ----
    const int c  = lane & 31;
    const int ch = lane >> 5;
    const int gx = ox + c;
    const int cc = (gx == 0) ? 0 : ((gx == 191) ? 2 : 1);
    const int r0 = wv * 4;

    v16i acc[4] = {};
#pragma unroll
    for (int dyr = 0; dyr < 6; ++dyr) {
        const int xrow = r0 + dyr;
        const v4i bf0 = xkv[(xrow * 34 + c + 0) * 3 + ch];
        const v4i bf1 = xkv[(xrow * 34 + c + 1) * 3 + ch];
        const v4i bf2 = xkv[(xrow * 34 + c + 2) * 3 + ch];
#pragma unroll
        for (int m = 0; m < 4; ++m) {
            const int dy = dyr - m;
            if (dy >= 0 && dy < 3) {
                acc[m] = __builtin_amdgcn_mfma_i32_32x32x32_i8(wfr[dy * 3 + 0], bf0, acc[m], 0, 0, 0);
                acc[m] = __builtin_amdgcn_mfma_i32_32x32x32_i8(wfr[dy * 3 + 1], bf1, acc[m], 0, 0, 0);
                acc[m] = __builtin_amdgcn_mfma_i32_32x32x32_i8(wfr[dy * 3 + 2], bf2, acc[m], 0, 0, 0);
            }
        }
    }

#pragma unroll
    for (int m = 0; m < 4; ++m) {
        const int r  = r0 + m;
        const int gy = oy + r;
        int k1 = 0;
#pragma unroll
        for (int dy = 0; dy < 3; ++dy)
#pragma unroll
            for (int dx = 0; dx < 3; ++dx)
                k1 += (int)cs2s[(r + dy) * 34 + (c + dx)];
        const int rc = (gy == 0) ? 0 : ((gy == 191) ? 2 : 1);
        const int cls = rc * 3 + cc;
        const float t2 = C2 * (float)k1;
#pragma unroll
        for (int reg = 0; reg < 16; ++reg) {
            const int co = (reg & 3) + 8 * (reg >> 2) + 4 * ch;
            const float y = fmaf(C1, (float)acc[m][reg], t2 + tlds[cls * 32 + co]);
            out[(((size_t)n * 32 + co) * 192 + gy) * 192 + gx] = y;
        }
    }
}

// ---------------- Fallback path (small ws): kB2 + fused conv (r7/r8 proven) ----------------
__global__ __launch_bounds__(256) void kB2_stats_tbl(
    const float* __restrict__ bias, const int* __restrict__ bits,
    const float* __restrict__ partials, const int* __restrict__ colJ,
    const float* __restrict__ wstats,
    float* __restrict__ gstats, float* __restrict__ coefs, float* __restrict__ tbl)
{
    __shared__ float bmn[32], bmx[32];
    __shared__ float s_gmn[3], s_gs[3];
    const int tid = threadIdx.x;
    const float wmv = wstats[0], wxv = wstats[1];

    if (tid < 32) {
        float mn = INFINITY, mx = -INFINITY;
        for (int i = 0; i < 36; ++i) {
            mn = fminf(mn, partials[(tid * 36 + i) * 2 + 0]);
            mx = fmaxf(mx, partials[(tid * 36 + i) * 2 + 1]);
        }
        bmn[tid] = mn; bmx[tid] = mx;
    }
    __syncthreads();

    if (tid < 3) {
        const int bval = 2 << tid;
        const float denom = (float)((1 << bval) - 1);
        float mn = INFINITY, mx = -INFINITY; bool has = false;
        for (int nb = 0; nb < 32; ++nb) {
            if (bits[nb] == bval) { has = true; mn = fminf(mn, bmn[nb]); mx = fmaxf(mx, bmx[nb]); }
        }
        if (!has) { mn = 0.f; mx = 0.f; }
        const float scale = fmaxf((mx - mn) / denom, EPSQ);
        gstats[tid * 2 + 0] = mn;
        gstats[tid * 2 + 1] = scale;
        s_gmn[tid] = mn; s_gs[tid] = scale;

        const float t = fmaxf((wxv - wmv) / denom, EPSQ);
        const int sig = 1 << (bval - 1);
        const double B_ = (double)wmv + (double)sig * (double)t;
        coefs[tid * 2 + 0] = (float)((double)scale * (double)t);
        coefs[tid * 2 + 1] = (float)((double)scale * B_);
    }
    __syncthreads();

    for (int idx = tid; idx < 864; idx += 256) {
        const int g   = idx / 288;
        const int rem = idx % 288;
        const int cls = rem / 32;
        const int co  = rem % 32;
        const int bval = 2 << g;
        const float denom = (float)((1 << bval) - 1);
        const float t = fmaxf((wxv - wmv) / denom, EPSQ);
        const int sig = 1 << (bval - 1);
        const double A_ = (double)s_gmn[g] + (double)sig * (double)s_gs[g];
        const double B_ = (double)wmv + (double)sig * (double)t;
        const int rc = cls / 3, cc = cls % 3;
        double js = 0.0, ij = 0.0; int ninv = 0;
        for (int tap = 0; tap < 9; ++tap) {
            const int dy = tap / 3, dx = tap % 3;
            const int cj = colJ[g * 288 + tap * 32 + co];
            js += (double)cj;
            const bool inv = (rc == 0 && dy == 0) || (rc == 2 && dy == 2) ||
                             (cc == 0 && dx == 0) || (cc == 2 && dx == 2);
            if (inv) { ++ninv; ij += (double)cj; }
        }
        const double v = (double)t * A_ * js + 288.0 * A_ * B_ + (double)bias[co]
                       - A_ * (32.0 * B_ * (double)ninv + (double)t * ij);
        tbl[idx] = (float)v;
    }
}

__global__ __launch_bounds__(256, 4) void kC_fused(
    const float* __restrict__ x, const int* __restrict__ bits,
    const float* __restrict__ gstats, const float* __restrict__ coefs,
    const float* __restrict__ tbl, const unsigned int* __restrict__ wq8,
    float* __restrict__ out)
{
    __shared__ v4i   xkv[18 * 34 * 3];
    __shared__ short cs2s[18 * 34];
    __shared__ float tlds[288];

    const int n  = blockIdx.z;
    const int oy = blockIdx.y * 16;
    const int ox = blockIdx.x * 32;
    const int tid  = threadIdx.x;
    const int lane = tid & 63;
    const int wv   = tid >> 6;

    const int bval = bits[n];
    const int g = (bval == 2) ? 0 : (bval == 4 ? 1 : 2);
    const int sig = 1 << (bval - 1);
    const float mn = gstats[g * 2 + 0];
    const float s  = gstats[g * 2 + 1];
    const float C1 = coefs[g * 2 + 0];
    const float C2 = coefs[g * 2 + 1];

    const v4i* wA = (const v4i*)(wq8 + (size_t)g * 2304);
    v4i wfr[9];
#pragma unroll
    for (int t = 0; t < 9; ++t) wfr[t] = wA[t * 64 + lane];

    for (int i = tid; i < 288; i += 256) tlds[i] = tbl[g * 288 + i];

    const float* xn = x + (size_t)n * 1179648;
    char* xk = (char*)xkv;
    for (int px = tid; px < 612; px += 256) {
        const int r = px / 34;
        const int c = px - r * 34;
        const int gy = oy + r - 1, gx = ox + c - 1;
        const bool valid = ((unsigned)gy < 192u) && ((unsigned)gx < 192u);
        const float* xp = xn + (size_t)(valid ? gy : 0) * 192 + (valid ? gx : 0);
        int ksum = 0;
        v4i pk0, pk1;
#pragma unroll
        for (int h = 0; h < 2; ++h) {
            float v[16];
#pragma unroll
            for (int i = 0; i < 16; ++i) v[i] = xp[(size_t)(h * 16 + i) * 36864];
            int w4[4];
#pragma unroll
            for (int q4 = 0; q4 < 4; ++q4) {
                unsigned int pw = 0;
#pragma unroll
                for (int b = 0; b < 4; ++b) {
                    int kq = (int)rintf((v[q4 * 4 + b] - mn) / s) - sig;
                    kq = kq < -128 ? -128 : (kq > 127 ? 127 : kq);
                    ksum += kq;
                    pw |= ((unsigned int)(unsigned char)(char)kq) << (8 * b);
                }
                w4[q4] = (int)pw;
            }
            if (h == 0) pk0 = (v4i){w4[0], w4[1], w4[2], w4[3]};
            else        pk1 = (v4i){w4[0], w4[1], w4[2], w4[3]};
        }
        if (!valid) { pk0 = (v4i){0,0,0,0}; pk1 = (v4i){0,0,0,0}; ksum = 0; }
        *(v4i*)(xk + px * 48 +  0) = pk0;
        *(v4i*)(xk + px * 48 + 16) = pk1;
        cs2s[px] = (short)ksum;
    }
    __syncthreads();

    const int c  = lane & 31;
    const int ch = lane >> 5;
    const int gx = ox + c;
    const int cc = (gx == 0) ? 0 : ((gx == 191) ? 2 : 1);
    const int r0 = wv * 4;

    v16i acc[4] = {};
#pragma unroll
    for (int dyr = 0; dyr < 6; ++dyr) {
        const int xrow = r0 + dyr;
        const v4i bf0 = xkv[(xrow * 34 + c + 0) * 3 + ch];
        const v4i bf1 = xkv[(xrow * 34 + c + 1) * 3 + ch];
        const v4i bf2 = xkv[(xrow * 34 + c + 2) * 3 + ch];
#pragma unroll
        for (int m = 0; m < 4; ++m) {
            const int dy = dyr - m;
            if (dy >= 0 && dy < 3) {
                acc[m] = __builtin_amdgcn_mfma_i32_32x32x32_i8(wfr[dy * 3 + 0], bf0, acc[m], 0, 0, 0);
                acc[m] = __builtin_amdgcn_mfma_i32_32x32x32_i8(wfr[dy * 3 + 1], bf1, acc[m], 0, 0, 0);
                acc[m] = __builtin_amdgcn_mfma_i32_32x32x32_i8(wfr[dy * 3 + 2], bf2, acc[m], 0, 0, 0);
            }
        }
    }

#pragma unroll
    for (int m = 0; m < 4; ++m) {
        const int r  = r0 + m;
        const int gy = oy + r;
        int k1 = 0;
#pragma unroll
        for (int dy = 0; dy < 3; ++dy)
#pragma unroll
            for (int dx = 0; dx < 3; ++dx)
                k1 += (int)cs2s[(r + dy) * 34 + (c + dx)];
        const int rc = (gy == 0) ? 0 : ((gy == 191) ? 2 : 1);
        const int cls = rc * 3 + cc;
        const float t2 = C2 * (float)k1;
#pragma unroll
        for (int reg = 0; reg < 16; ++reg) {
            const int co = (reg & 3) + 8 * (reg >> 2) + 4 * ch;
            const float y = fmaf(C1, (float)acc[m][reg], t2 + tlds[cls * 32 + co]);
            out[(((size_t)n * 32 + co) * 192 + gy) * 192 + gx] = y;
        }
    }
}

extern "C" void kernel_launch(void* const* d_in, const int* in_sizes, int n_in,
                              void* d_out, int out_size, void* d_ws, size_t ws_size,
                              hipStream_t stream) {
    const float* x      = (const float*)d_in[0];
    const float* weight = (const float*)d_in[1];
    const float* bias   = (const float*)d_in[2];
    const int*   bits   = (const int*)d_in[3];
    float* out = (float*)d_out;

    float* ws       = (float*)d_ws;
    float* partials = ws;                            // 2304 floats
    float* gstats   = ws + 2304;                     // 8   (fallback only)
    float* coefs    = ws + 2312;                     // 8   (fallback only)
    float* tbl      = ws + 2320;                     // 864 (fallback only)
    int*   colJ     = (int*)(ws + 3184);             // 864 ints
    unsigned int* wq8 = (unsigned int*)(ws + 4048);  // 6912 u32
    float* wstats   = ws + 10960;                    // 2 floats
    const size_t codes_off   = 43904;                // 64B-aligned
    const size_t codes_bytes = 37748736ull;
    unsigned int* codes = (unsigned int*)((char*)d_ws + codes_off);
    const bool big_ws = ws_size >= codes_off + codes_bytes;

    kAW<<<1179, 256, 0, stream>>>(x, weight, partials, wq8, colJ, wstats);

    dim3 grid(6, 12, 32);
    if (big_ws) {
        kQ_quant<<<32 * 36, 256, 0, stream>>>(x, bits, partials, codes);
        kC_codes<<<grid, 256, 0, stream>>>(codes, bits, partials, colJ, wstats, bias, wq8, out);
    } else {
        kB2_stats_tbl<<<1, 256, 0, stream>>>(bias, bits, partials, colJ, wstats, gstats, coefs, tbl);
        kC_fused<<<grid, 256, 0, stream>>>(x, bits, gstats, coefs, tbl, wq8, out);
    }
}